// Round 7
// baseline (5120.957 us; speedup 1.0000x reference)
//
#include <hip/hip_runtime.h>

#define NN 30000
#define EE 480000

// ---------- zero-fill fallback (ws too small diagnostic) ----------
__global__ __launch_bounds__(256) void k_zero(float* __restrict__ out, int n){
  int i = blockIdx.x*256 + threadIdx.x;
  if (i < n) out[i] = 0.f;
}

// ---------- node feature init: fA[N][288] (row0=node_l0, rest 0), hist=0 ----------
__global__ __launch_bounds__(256) void k_init(
    const float* __restrict__ nl0, float* __restrict__ fA, int* __restrict__ hist)
{
  int i = blockIdx.x*256 + threadIdx.x;   // exactly N*288
  int n = i/288; int r2 = i - n*288;
  fA[i] = (r2 < 32) ? nl0[(size_t)n*32 + r2] : 0.f;
  if (i < NN) hist[i] = 0;
}

__global__ __launch_bounds__(256) void k_hist(const int* __restrict__ dst, int* __restrict__ hist){
  int e = blockIdx.x*256 + threadIdx.x;
  if (e < EE) atomicAdd(&hist[dst[e]], 1);
}

// single-block exclusive scan over hist[NN] -> offs, cursor
__global__ void k_scan(const int* __restrict__ hist, int* __restrict__ offs,
                       int* __restrict__ cursor, int n)
{
  __shared__ int sm[1024];
  __shared__ int carry;
  int tid = threadIdx.x;
  if (tid==0) carry = 0;
  __syncthreads();
  for (int base=0; base<n; base+=1024){
    int i = base + tid;
    int v = (i<n)? hist[i] : 0;
    sm[tid] = v; __syncthreads();
    for (int o=1;o<1024;o<<=1){
      int tv = (tid>=o)? sm[tid-o] : 0;
      __syncthreads();
      sm[tid] += tv;
      __syncthreads();
    }
    int cy = carry;
    int excl = sm[tid] - v;
    if (i<n){ offs[i] = cy+excl; cursor[i] = cy+excl; }
    __syncthreads();
    if (tid==1023) carry = cy + sm[1023];
    __syncthreads();
  }
  if (tid==0) offs[n] = carry;
}

__global__ __launch_bounds__(256) void k_scatter(const int* __restrict__ dst,
    int* __restrict__ cursor, int* __restrict__ perm)
{
  int e = blockIdx.x*256 + threadIdx.x;
  if (e >= EE) return;
  int d = dst[e];
  int p = atomicAdd(&cursor[d], 1);
  perm[p] = e;
}

// ---------- per-node q projection folded into T ----------
__global__ __launch_bounds__(256) void k_qt(
    const float* __restrict__ f_in, const float* __restrict__ Wqf,
    const float* __restrict__ Wkf, float* __restrict__ Tq)
{
  __shared__ float WqL[1024];
  __shared__ float WkL[1056];           // [c][33] padded
  int tid = threadIdx.x;
  for (int i=tid;i<1024;i+=256) WqL[i]=Wqf[i];
  for (int i=tid;i<1056;i+=256){ int r=i/33, o=i-r*33; if (o<32) WkL[i]=Wkf[r*32+o]; }
  __syncthreads();
  int n = blockIdx.x*8 + (tid>>5), c = tid&31;
  const float* f0 = f_in + (size_t)n*288;
  float q=0.f;
  #pragma unroll
  for (int ci=0;ci<32;ci++) q = fmaf(f0[ci], WqL[ci*32+c], q);
  float t0=0.f,t1=0.f,t2=0.f,t3=0.f;
  #pragma unroll
  for (int j=0;j<32;j++){
    float qb = __shfl(q, j, 32);
    float wv = WkL[c*33 + j];
    if (j<8)       t0 = fmaf(wv, qb, t0);
    else if (j<16) t1 = fmaf(wv, qb, t1);
    else if (j<24) t2 = fmaf(wv, qb, t2);
    else           t3 = fmaf(wv, qb, t3);
  }
  float* T = Tq + (size_t)n*128;
  T[c]=t0; T[32+c]=t1; T[64+c]=t2; T[96+c]=t3;
}

// ---------- zero agg buffer + den ----------
__global__ __launch_bounds__(256) void k_zeroagg(float* __restrict__ fo, float* __restrict__ den){
  int i = blockIdx.x*256 + threadIdx.x;
  fo[i] = 0.f;
  if (i < NN*4) den[i] = 0.f;
}

// DPP reduction helper: x += value from partner lane (involutive perm), VALU pipe.
// 0xB1=quad xor1, 0x4E=quad xor2, 0x141=row_half_mirror (pairs across 4-groups
// within 8), 0x140=row_mirror (pairs across 8-groups within 16). For sum
// reduction any involution pairing complementary groups works.
template<int CTRL>
__device__ __forceinline__ float dpp_add(float x){
  return x + __int_as_float(__builtin_amdgcn_mov_dpp(__float_as_int(x), CTRL, 0xF, 0xF, true));
}
__device__ __forceinline__ float red32(float p){
  p = dpp_add<0xB1>(p);
  p = dpp_add<0x4E>(p);
  p = dpp_add<0x141>(p);
  p = dpp_add<0x140>(p);
  p += __shfl_xor(p, 16, 32);
  return p;
}

// ---------- fused edge pass: 4 edges/wave-iteration, 3 waves/SIMD ----------
// Register diet vs R6: W1 column in LDS (-34 regs), f1..f8 loaded on-demand at
// iteration start instead of prefetched (-16 live regs). Pipeline carries only
// e,s,d,rv,f0,T per edge. DPP 4-stage butterfly (+shfl_xor16) cuts bperms 24->8.
template<int FIRST>
__global__ __launch_bounds__(256,3) void k_fused(
    const float* __restrict__ pos, const float* __restrict__ ef,
    const int* __restrict__ src, const int* __restrict__ dst,
    const int* __restrict__ perm,
    const float* __restrict__ f_in, const float* __restrict__ Tq,
    const float* __restrict__ Wr1g, const float* __restrict__ br1g,
    const float* __restrict__ Wr2g,
    float* __restrict__ aggG, float* __restrict__ den)
{
  __shared__ __align__(16) float W2A[4096];
  __shared__ __align__(16) float W2B[FIRST ? 4 : 4096];
  __shared__ float W1L[1056];          // [33][32], stride-1 reads: conflict-free
  __shared__ __align__(16) float rvL[4][4][32];
  __shared__ __align__(16) float hL [4][4][32];
  __shared__ float4 geoL[4][16];
  int tid = threadIdx.x;
  if (FIRST){
    for (int t=tid;t<4096;t+=256){
      int ci=t>>7, r=t&127, c0=r>>2, j=r&3;
      int k = (j==0)?0:((j==1)?3:((j==2)?5:-1));
      W2A[t] = (k>=0)? Wr2g[ci*224 + k*32 + c0] : 0.f;
    }
  } else {
    for (int t=tid;t<4096;t+=256){
      int ci=t>>7, r=t&127, c0=r>>2, j=r&3;
      W2A[t] = Wr2g[ci*224 + j*32 + c0];
      int k = j+4;
      W2B[t] = (k<7)? Wr2g[ci*224 + k*32 + c0] : 0.f;
    }
  }
  for (int i=tid;i<1056;i+=256) W1L[i] = Wr1g[i];
  __syncthreads();

  int lane = tid & 63;
  int wv   = tid >> 6;
  int c    = lane & 31;
  int half = lane >> 5;
  int hh   = c >> 3;
  int base = blockIdx.x*64 + wv*16;      // 7500*64 = 480000 exact
  int ll   = lane & 15;
  float b1 = br1g[c];

  // ---- lane-owned edge (ll); lanes 16..31 duplicate 0..15 ----
  int eL = perm[base + ll];
  int sL = src[eL];
  int dL = dst[eL];
  {
    float pdx = pos[dL*3+0]-pos[sL*3+0];
    float pdy = pos[dL*3+1]-pos[sL*3+1];
    float pdz = pos[dL*3+2]-pos[sL*3+2];
    float rr = sqrtf(pdx*pdx+pdy*pdy+pdz*pdz+1e-8f);
    float iv = 1.f/rr;
    if (lane < 16) geoL[wv][ll] = make_float4(rr, pdx*iv, pdy*iv, pdz*iv);
  }

  // ---- prologue gathers for iteration 0 (edges 2*half, 2*half+1) ----
  int sPa, sPb, dPa, dPb;
  float rvPa, rvPb, f0Pa, f0Pb;
  float Ta0,Ta1,Ta2,Ta3, Tb0,Tb1,Tb2,Tb3;
  {
    int eA = __shfl(eL, 2*half,   32);
    int eB = __shfl(eL, 2*half+1, 32);
    sPa = __shfl(sL, 2*half,   32);
    sPb = __shfl(sL, 2*half+1, 32);
    dPa = __shfl(dL, 2*half,   32);
    dPb = __shfl(dL, 2*half+1, 32);
    rvPa = ef[(size_t)eA*32 + c];
    rvPb = ef[(size_t)eB*32 + c];
    f0Pa = f_in[(size_t)sPa*288 + c];
    f0Pb = f_in[(size_t)sPb*288 + c];
    const float* TA = Tq + (size_t)dPa*128;
    const float* TB = Tq + (size_t)dPb*128;
    Ta0=TA[c]; Ta1=TA[32+c]; Ta2=TA[64+c]; Ta3=TA[96+c];
    Tb0=TB[c]; Tb1=TB[32+c]; Tb2=TB[64+c]; Tb3=TB[96+c];
  }

  float A[9];
  #pragma unroll
  for (int j=0;j<9;j++) A[j]=0.f;
  float denA = 0.f;
  int curd = -1;

  #pragma unroll 1
  for (int it=0; it<4; ++it){
    // ---- capture current ----
    int sCa=sPa, sCb=sPb, dCa=dPa, dCb=dPb;
    float f0A=f0Pa, f0B=f0Pb;
    float Sa0=Ta0,Sa1=Ta1,Sa2=Ta2,Sa3=Ta3;
    float Sb0=Tb0,Sb1=Tb1,Sb2=Tb2,Sb3=Tb3;
    rvL[wv][half*2+0][c] = rvPa;
    rvL[wv][half*2+1][c] = rvPb;

    // ---- on-demand f1..f8 for current edges (issued now, used after h/w loops) ----
    float ca1=0.f,ca2=0.f,ca3=0.f,ca4=0.f,ca5=0.f,ca6=0.f,ca7=0.f,ca8=0.f;
    float cb1=0.f,cb2=0.f,cb3=0.f,cb4=0.f,cb5=0.f,cb6=0.f,cb7=0.f,cb8=0.f;
    if (!FIRST){
      const float* fsA = f_in + (size_t)sCa*288;
      const float* fsB = f_in + (size_t)sCb*288;
      ca1=fsA[32+c]; ca2=fsA[64+c]; ca3=fsA[96+c]; ca4=fsA[128+c];
      ca5=fsA[160+c]; ca6=fsA[192+c]; ca7=fsA[224+c]; ca8=fsA[256+c];
      cb1=fsB[32+c]; cb2=fsB[64+c]; cb3=fsB[96+c]; cb4=fsB[128+c];
      cb5=fsB[160+c]; cb6=fsB[192+c]; cb7=fsB[224+c]; cb8=fsB[256+c];
    }

    // ---- branchless prefetch of iteration it+1 (it=3 -> lanes 16..19 dummy) ----
    {
      int ia = (it+1)*4 + 2*half, ib = ia+1;
      int eNa = __shfl(eL, ia, 32);
      int eNb = __shfl(eL, ib, 32);
      sPa = __shfl(sL, ia, 32); sPb = __shfl(sL, ib, 32);
      dPa = __shfl(dL, ia, 32); dPb = __shfl(dL, ib, 32);
      rvPa = ef[(size_t)eNa*32 + c];
      rvPb = ef[(size_t)eNb*32 + c];
      f0Pa = f_in[(size_t)sPa*288 + c];
      f0Pb = f_in[(size_t)sPb*288 + c];
      const float* TA2 = Tq + (size_t)dPa*128;
      const float* TB2 = Tq + (size_t)dPb*128;
      Ta0=TA2[c]; Ta1=TA2[32+c]; Ta2=TA2[64+c]; Ta3=TA2[96+c];
      Tb0=TB2[c]; Tb1=TB2[32+c]; Tb2=TB2[64+c]; Tb3=TB2[96+c];
    }

    // ---- geometry for current edges (uniform-per-half LDS read) ----
    int ei = it*4 + 2*half;
    float4 ga = geoL[wv][ei];
    float4 gb = geoL[wv][ei+1];

    // ---- h for both edges (W1 from LDS, rv via uniform float4 LDS reads) ----
    float ha0 = fmaf(ga.x, W1L[c], b1), ha1=0.f, ha2=0.f, ha3=0.f;
    float hb0 = fmaf(gb.x, W1L[c], b1), hb1=0.f, hb2=0.f, hb3=0.f;
    #pragma unroll
    for (int jb=0;jb<8;jb++){
      float4 ra = *(const float4*)&rvL[wv][half*2+0][jb*4];
      float4 rb = *(const float4*)&rvL[wv][half*2+1][jb*4];
      float wj0 = W1L[(1+jb*4+0)*32 + c];
      float wj1 = W1L[(1+jb*4+1)*32 + c];
      float wj2 = W1L[(1+jb*4+2)*32 + c];
      float wj3 = W1L[(1+jb*4+3)*32 + c];
      ha0 = fmaf(ra.x, wj0, ha0);
      ha1 = fmaf(ra.y, wj1, ha1);
      ha2 = fmaf(ra.z, wj2, ha2);
      ha3 = fmaf(ra.w, wj3, ha3);
      hb0 = fmaf(rb.x, wj0, hb0);
      hb1 = fmaf(rb.y, wj1, hb1);
      hb2 = fmaf(rb.z, wj2, hb2);
      hb3 = fmaf(rb.w, wj3, hb3);
    }
    float hA = fmaxf((ha0+ha1)+(ha2+ha3), 0.f);
    float hB = fmaxf((hb0+hb1)+(hb2+hb3), 0.f);
    hL[wv][half*2+0][c] = hA;
    hL[wv][half*2+1][c] = hB;

    // ---- w = h @ W2 for both edges; W2 reads amortized over 4 edges ----
    float wa0=0.f,wa1=0.f,wa2=0.f,wa3=0.f,wa4=0.f,wa5=0.f,wa6=0.f;
    float wb0=0.f,wb1=0.f,wb2=0.f,wb3=0.f,wb4=0.f,wb5=0.f,wb6=0.f;
    #pragma unroll
    for (int c4=0;c4<8;c4++){
      float4 ha4 = *(const float4*)&hL[wv][half*2+0][c4*4];
      float4 hb4 = *(const float4*)&hL[wv][half*2+1][c4*4];
      #pragma unroll
      for (int j=0;j<4;j++){
        int ci = c4*4+j;
        float haj = (j==0)?ha4.x:((j==1)?ha4.y:((j==2)?ha4.z:ha4.w));
        float hbj = (j==0)?hb4.x:((j==1)?hb4.y:((j==2)?hb4.z:hb4.w));
        float4 qa = *(const float4*)&W2A[ci*128 + c*4];
        if (FIRST){
          wa0 = fmaf(haj, qa.x, wa0); wa3 = fmaf(haj, qa.y, wa3); wa5 = fmaf(haj, qa.z, wa5);
          wb0 = fmaf(hbj, qa.x, wb0); wb3 = fmaf(hbj, qa.y, wb3); wb5 = fmaf(hbj, qa.z, wb5);
        } else {
          float4 qb = *(const float4*)&W2B[ci*128 + c*4];
          wa0 = fmaf(haj, qa.x, wa0); wa1 = fmaf(haj, qa.y, wa1);
          wa2 = fmaf(haj, qa.z, wa2); wa3 = fmaf(haj, qa.w, wa3);
          wa4 = fmaf(haj, qb.x, wa4); wa5 = fmaf(haj, qb.y, wa5);
          wa6 = fmaf(haj, qb.z, wa6);
          wb0 = fmaf(hbj, qa.x, wb0); wb1 = fmaf(hbj, qa.y, wb1);
          wb2 = fmaf(hbj, qa.z, wb2); wb3 = fmaf(hbj, qa.w, wb3);
          wb4 = fmaf(hbj, qb.x, wb4); wb5 = fmaf(hbj, qb.y, wb5);
          wb6 = fmaf(hbj, qb.z, wb6);
        }
      }
    }

    // ---- messages ----
    float y2aA=ga.y*ga.z, y2bA=ga.z*ga.w, y2cA=3.f*ga.w*ga.w-1.f, y2dA=ga.y*ga.w, y2eA=ga.y*ga.y-ga.z*ga.z;
    float y2aB=gb.y*gb.z, y2bB=gb.z*gb.w, y2cB=3.f*gb.w*gb.w-1.f, y2dB=gb.y*gb.w, y2eB=gb.y*gb.y-gb.z*gb.z;
    float m0A = wa0*f0A;
    float m0B = wb0*f0B;
    if (!FIRST){
      m0A += wa1*(ca1*ga.y+ca2*ga.z+ca3*ga.w)
           + wa2*(ca4*y2aA+ca5*y2bA+ca6*y2cA+ca7*y2dA+ca8*y2eA);
      m0B += wb1*(cb1*gb.y+cb2*gb.z+cb3*gb.w)
           + wb2*(cb4*y2aB+cb5*y2bB+cb6*y2cB+cb7*y2dB+cb8*y2eB);
    }

    // ---- logits: per-lane products + DPP butterfly (1 bperm stage) ----
    float pa0 = red32(m0A*Sa0), pa1 = red32(m0A*Sa1);
    float pa2 = red32(m0A*Sa2), pa3 = red32(m0A*Sa3);
    float pb0 = red32(m0B*Sb0), pb1 = red32(m0B*Sb1);
    float pb2 = red32(m0B*Sb2), pb3 = red32(m0B*Sb3);
    float ShA = (hh==0)?pa0:((hh==1)?pa1:((hh==2)?pa2:pa3));
    float ShB = (hh==0)?pb0:((hh==1)?pb1:((hh==2)?pb2:pb3));
    float elA = __expf(ShA * 0.35355339059327373f);
    float elB = __expf(ShB * 0.35355339059327373f);

    // ---- edge A: flush + accumulate ----
    if (dCa != curd){
      if (curd >= 0){
        #pragma unroll
        for (int j=0;j<9;j++) atomicAdd(&aggG[(size_t)curd*288 + j*32 + c], A[j]);
        if ((c&7)==0) atomicAdd(&den[(size_t)curd*4 + hh], denA);
      }
      #pragma unroll
      for (int j=0;j<9;j++) A[j]=0.f;
      denA = 0.f;
      curd = dCa;
    }
    denA += elA;
    A[0] = fmaf(elA, m0A, A[0]);
    A[1] = fmaf(elA, wa3*f0A*ga.y + wa4*ca1, A[1]);
    A[2] = fmaf(elA, wa3*f0A*ga.z + wa4*ca2, A[2]);
    A[3] = fmaf(elA, wa3*f0A*ga.w + wa4*ca3, A[3]);
    A[4] = fmaf(elA, wa5*f0A*y2aA + wa6*ca4, A[4]);
    A[5] = fmaf(elA, wa5*f0A*y2bA + wa6*ca5, A[5]);
    A[6] = fmaf(elA, wa5*f0A*y2cA + wa6*ca6, A[6]);
    A[7] = fmaf(elA, wa5*f0A*y2dA + wa6*ca7, A[7]);
    A[8] = fmaf(elA, wa5*f0A*y2eA + wa6*ca8, A[8]);

    // ---- edge B: flush + accumulate ----
    if (dCb != curd){
      if (curd >= 0){
        #pragma unroll
        for (int j=0;j<9;j++) atomicAdd(&aggG[(size_t)curd*288 + j*32 + c], A[j]);
        if ((c&7)==0) atomicAdd(&den[(size_t)curd*4 + hh], denA);
      }
      #pragma unroll
      for (int j=0;j<9;j++) A[j]=0.f;
      denA = 0.f;
      curd = dCb;
    }
    denA += elB;
    A[0] = fmaf(elB, m0B, A[0]);
    A[1] = fmaf(elB, wb3*f0B*gb.y + wb4*cb1, A[1]);
    A[2] = fmaf(elB, wb3*f0B*gb.z + wb4*cb2, A[2]);
    A[3] = fmaf(elB, wb3*f0B*gb.w + wb4*cb3, A[3]);
    A[4] = fmaf(elB, wb5*f0B*y2aB + wb6*cb4, A[4]);
    A[5] = fmaf(elB, wb5*f0B*y2bB + wb6*cb5, A[5]);
    A[6] = fmaf(elB, wb5*f0B*y2cB + wb6*cb6, A[6]);
    A[7] = fmaf(elB, wb5*f0B*y2dB + wb6*cb7, A[7]);
    A[8] = fmaf(elB, wb5*f0B*y2eB + wb6*cb8, A[8]);
  }
  if (curd >= 0){
    #pragma unroll
    for (int j=0;j<9;j++) atomicAdd(&aggG[(size_t)curd*288 + j*32 + c], A[j]);
    if ((c&7)==0) atomicAdd(&den[(size_t)curd*4 + hh], denA);
  }
}

// ---------- node update ----------
__global__ __launch_bounds__(256) void k_update(
    const float* __restrict__ aggG, const float* __restrict__ f_in,
    const float* __restrict__ den,
    const float* __restrict__ Ws0, const float* __restrict__ Ws1,
    const float* __restrict__ Ws2, const float* __restrict__ Wsk,
    float* __restrict__ f_out)
{
  __shared__ float wL[4096];
  __shared__ float agL[8][297];
  __shared__ float f0L[8][33];
  __shared__ float dL[8][4];
  int tid = threadIdx.x;
  int nb = blockIdx.x*8;
  for (int i=tid;i<1024;i+=256){
    wL[i]=Ws0[i]; wL[1024+i]=Ws1[i]; wL[2048+i]=Ws2[i]; wL[3072+i]=Wsk[i];
  }
  if (tid < 32){
    int nl = tid>>2, hd = tid&3;
    dL[nl][hd] = 1.f/(den[(size_t)(nb+nl)*4 + hd] + 1e-30f);
  }
  { int nl=tid>>5, cc=tid&31; f0L[nl][cc] = f_in[(size_t)(nb+nl)*288 + cc]; }
  __syncthreads();
  for (int i=tid;i<2304;i+=256){
    int nl=i/288, F=i-nl*288, r=F>>5, cc=F&31;
    agL[nl][r*33+cc] = aggG[(size_t)(nb+nl)*288 + F] * dL[nl][cc>>3];
  }
  __syncthreads();
  int nl = tid>>5, o = tid&31;
  size_t obase = (size_t)(nb+nl)*288;
  #pragma unroll 1
  for (int r=0;r<9;r++){
    const float* W = (r==0)? wL : ((r<4)? wL+1024 : wL+2048);
    float acc=0.f;
    #pragma unroll
    for (int cc=0;cc<32;cc++) acc = fmaf(agL[nl][r*33+cc], W[cc*32+o], acc);
    if (r==0){
      #pragma unroll
      for (int cc=0;cc<32;cc++) acc = fmaf(f0L[nl][cc], wL[3072 + cc*32+o], acc);
    }
    f_out[obase + r*32 + o] = acc;
  }
}

// ---------- output head (f32 out) ----------
__global__ __launch_bounds__(256) void k_out(
    const float* __restrict__ f_in, const float* __restrict__ Wout,
    const float* __restrict__ Wc, float* __restrict__ out)
{
  __shared__ float sh[8][33];
  int tid = threadIdx.x;
  int nl = tid>>5, c = tid&31;
  int n = blockIdx.x*8 + nl;
  const float* f0 = f_in + (size_t)n*288;
  float acc=0.f;
  #pragma unroll
  for (int ci=0;ci<32;ci++) acc = fmaf(f0[ci], Wout[ci*32+c], acc);
  out[(size_t)n*32 + c] = acc;
  sh[nl][c] = acc;
  __syncthreads();
  if (tid < 120){
    int nl2 = tid/15, j = tid%15;
    int n2 = blockIdx.x*8 + nl2;
    float a = 0.f;
    #pragma unroll
    for (int ci=0;ci<32;ci++) a = fmaf(sh[nl2][ci], Wc[ci*15+j], a);
    out[(size_t)NN*32 + (size_t)n2*15 + j] = a;
  }
}

extern "C" void kernel_launch(void* const* d_in, const int* in_sizes, int n_in,
                              void* d_out, int out_size, void* d_ws, size_t ws_size,
                              hipStream_t stream)
{
  (void)in_sizes; (void)n_in;
  const float* pos       = (const float*)d_in[0];
  const float* node_l0   = (const float*)d_in[1];
  const float* edge_feat = (const float*)d_in[2];
  const int* esrc = (const int*)d_in[3];
  const int* edst = (const int*)d_in[4];
  const float* Wr1  = (const float*)d_in[5];
  const float* br1  = (const float*)d_in[6];
  const float* Wr2  = (const float*)d_in[7];
  const float* Wq   = (const float*)d_in[8];
  const float* Wk   = (const float*)d_in[9];
  const float* Ws0  = (const float*)d_in[10];
  const float* Ws1  = (const float*)d_in[11];
  const float* Ws2  = (const float*)d_in[12];
  const float* Wsk  = (const float*)d_in[13];
  const float* Wout = (const float*)d_in[14];
  const float* Wc   = (const float*)d_in[15];

  char* ws = (char*)d_ws;
  size_t off = 0;
  auto take = [&](size_t bytes)->char*{
    char* p = ws + off;
    off += (bytes + 255) & ~(size_t)255;
    return p;
  };
  float* fA      = (float*)take((size_t)NN*288*4);
  float* fB      = (float*)take((size_t)NN*288*4);
  float* Tq      = (float*)take((size_t)NN*128*4);
  int*   hist    = (int*)  take((size_t)NN*4);
  int*   offs    = (int*)  take((size_t)(NN+1)*4);
  int*   cursor  = (int*)  take((size_t)NN*4);
  int*   perm    = (int*)  take((size_t)EE*4);
  float* den     = (float*)take((size_t)NN*4*4);
  size_t need = off;                                  // ~88 MB

  if (ws_size < need){
    k_zero<<<(out_size+255)/256,256,0,stream>>>((float*)d_out, out_size);
    return;
  }

  k_init<<<33750,256,0,stream>>>(node_l0, fA, hist);
  k_hist<<<1875,256,0,stream>>>(edst, hist);
  k_scan<<<1,1024,0,stream>>>(hist, offs, cursor, NN);
  k_scatter<<<1875,256,0,stream>>>(edst, cursor, perm);

  float* fi = fA; float* fo = fB;
  for (int l=0; l<2; ++l){
    k_zeroagg<<<33750,256,0,stream>>>(fo, den);
    k_qt<<<3750,256,0,stream>>>(fi, Wq + l*1024, Wk + l*1024, Tq);
    if (l==0){
      k_fused<1><<<7500,256,0,stream>>>(pos, edge_feat, esrc, edst, perm,
          fi, Tq, Wr1 + l*1056, br1 + l*32, Wr2 + l*7168,
          fo, den);
    } else {
      k_fused<0><<<7500,256,0,stream>>>(pos, edge_feat, esrc, edst, perm,
          fi, Tq, Wr1 + l*1056, br1 + l*32, Wr2 + l*7168,
          fo, den);
    }
    k_update<<<3750,256,0,stream>>>(fo, fi, den,
        Ws0 + l*1024, Ws1 + l*1024, Ws2 + l*1024, Wsk + l*1024, fo);
    float* tmp = fi; fi = fo; fo = tmp;
  }
  k_out<<<3750,256,0,stream>>>(fi, Wout, Wc, (float*)d_out);
}

// Round 8
// 2164.564 us; speedup vs baseline: 2.3658x; 2.3658x over previous
//
#include <hip/hip_runtime.h>

#define NN 30000
#define EE 480000

// ---------- zero-fill fallback (ws too small diagnostic) ----------
__global__ __launch_bounds__(256) void k_zero(float* __restrict__ out, int n){
  int i = blockIdx.x*256 + threadIdx.x;
  if (i < n) out[i] = 0.f;
}

// ---------- node feature init: fA[N][288] (row0=node_l0, rest 0), hist=0 ----------
__global__ __launch_bounds__(256) void k_init(
    const float* __restrict__ nl0, float* __restrict__ fA, int* __restrict__ hist)
{
  int i = blockIdx.x*256 + threadIdx.x;   // exactly N*288
  int n = i/288; int r2 = i - n*288;
  fA[i] = (r2 < 32) ? nl0[(size_t)n*32 + r2] : 0.f;
  if (i < NN) hist[i] = 0;
}

__global__ __launch_bounds__(256) void k_hist(const int* __restrict__ dst, int* __restrict__ hist){
  int e = blockIdx.x*256 + threadIdx.x;
  if (e < EE) atomicAdd(&hist[dst[e]], 1);
}

// single-block exclusive scan over hist[NN] -> offs, cursor
__global__ void k_scan(const int* __restrict__ hist, int* __restrict__ offs,
                       int* __restrict__ cursor, int n)
{
  __shared__ int sm[1024];
  __shared__ int carry;
  int tid = threadIdx.x;
  if (tid==0) carry = 0;
  __syncthreads();
  for (int base=0; base<n; base+=1024){
    int i = base + tid;
    int v = (i<n)? hist[i] : 0;
    sm[tid] = v; __syncthreads();
    for (int o=1;o<1024;o<<=1){
      int tv = (tid>=o)? sm[tid-o] : 0;
      __syncthreads();
      sm[tid] += tv;
      __syncthreads();
    }
    int cy = carry;
    int excl = sm[tid] - v;
    if (i<n){ offs[i] = cy+excl; cursor[i] = cy+excl; }
    __syncthreads();
    if (tid==1023) carry = cy + sm[1023];
    __syncthreads();
  }
  if (tid==0) offs[n] = carry;
}

__global__ __launch_bounds__(256) void k_scatter(const int* __restrict__ dst,
    int* __restrict__ cursor, int* __restrict__ perm)
{
  int e = blockIdx.x*256 + threadIdx.x;
  if (e >= EE) return;
  int d = dst[e];
  int p = atomicAdd(&cursor[d], 1);
  perm[p] = e;
}

// ---------- per-node q projection folded into T ----------
__global__ __launch_bounds__(256) void k_qt(
    const float* __restrict__ f_in, const float* __restrict__ Wqf,
    const float* __restrict__ Wkf, float* __restrict__ Tq)
{
  __shared__ float WqL[1024];
  __shared__ float WkL[1056];           // [c][33] padded
  int tid = threadIdx.x;
  for (int i=tid;i<1024;i+=256) WqL[i]=Wqf[i];
  for (int i=tid;i<1056;i+=256){ int r=i/33, o=i-r*33; if (o<32) WkL[i]=Wkf[r*32+o]; }
  __syncthreads();
  int n = blockIdx.x*8 + (tid>>5), c = tid&31;
  const float* f0 = f_in + (size_t)n*288;
  float q=0.f;
  #pragma unroll
  for (int ci=0;ci<32;ci++) q = fmaf(f0[ci], WqL[ci*32+c], q);
  float t0=0.f,t1=0.f,t2=0.f,t3=0.f;
  #pragma unroll
  for (int j=0;j<32;j++){
    float qb = __shfl(q, j, 32);
    float wv = WkL[c*33 + j];
    if (j<8)       t0 = fmaf(wv, qb, t0);
    else if (j<16) t1 = fmaf(wv, qb, t1);
    else if (j<24) t2 = fmaf(wv, qb, t2);
    else           t3 = fmaf(wv, qb, t3);
  }
  float* T = Tq + (size_t)n*128;
  T[c]=t0; T[32+c]=t1; T[64+c]=t2; T[96+c]=t3;
}

// ---------- zero agg buffer + den ----------
__global__ __launch_bounds__(256) void k_zeroagg(float* __restrict__ fo, float* __restrict__ den){
  int i = blockIdx.x*256 + threadIdx.x;
  fo[i] = 0.f;
  if (i < NN*4) den[i] = 0.f;
}

// DPP reduction: x += partner (involutive perms), VALU pipe. Proven correct in R7.
template<int CTRL>
__device__ __forceinline__ float dpp_add(float x){
  return x + __int_as_float(__builtin_amdgcn_mov_dpp(__float_as_int(x), CTRL, 0xF, 0xF, true));
}
__device__ __forceinline__ float red32(float p){
  p = dpp_add<0xB1>(p);    // quad xor1
  p = dpp_add<0x4E>(p);    // quad xor2
  p = dpp_add<0x141>(p);   // row_half_mirror (pairs quads within 8)
  p = dpp_add<0x140>(p);   // row_mirror (pairs 8-groups within 16)
  p += __shfl_xor(p, 16, 32);
  return p;
}

// ---------- fused edge pass: 8 edges/wave-iteration (4 per half), 2 iterations ----------
// Plain launch_bounds(256): NEVER force occupancy (R7 spill disaster; waves/SIMD
// steps at VGPR 128/256 so "3 waves" is unreachable). DS diet instead:
// W2 ds_read_b128 stream amortized over 4 edges per half (12 b128/edge vs 20).
// Pipeline prefetch carries only {s,d,rv,f0} x4 edges; f1..f8 and T loaded
// on-demand at iteration start (issued ~1000cy before use). W1 in LDS
// (stride-1 conflict-free, spill insurance). Arrays fully unrolled -> static
// indices (rule: runtime-indexed reg arrays spill to scratch).
template<int FIRST>
__global__ __launch_bounds__(256) void k_fused(
    const float* __restrict__ pos, const float* __restrict__ ef,
    const int* __restrict__ src, const int* __restrict__ dst,
    const int* __restrict__ perm,
    const float* __restrict__ f_in, const float* __restrict__ Tq,
    const float* __restrict__ Wr1g, const float* __restrict__ br1g,
    const float* __restrict__ Wr2g,
    float* __restrict__ aggG, float* __restrict__ den)
{
  __shared__ __align__(16) float W2A[4096];
  __shared__ __align__(16) float W2B[FIRST ? 4 : 4096];
  __shared__ float W1L[1056];                    // [33][32] stride-1: conflict-free
  __shared__ __align__(16) float rvL[4][8][32];
  __shared__ __align__(16) float hL [4][8][32];
  __shared__ float4 geoL[4][16];
  int tid = threadIdx.x;
  if (FIRST){
    for (int t=tid;t<4096;t+=256){
      int ci=t>>7, r=t&127, c0=r>>2, j=r&3;
      int k = (j==0)?0:((j==1)?3:((j==2)?5:-1));
      W2A[t] = (k>=0)? Wr2g[ci*224 + k*32 + c0] : 0.f;
    }
  } else {
    for (int t=tid;t<4096;t+=256){
      int ci=t>>7, r=t&127, c0=r>>2, j=r&3;
      W2A[t] = Wr2g[ci*224 + j*32 + c0];
      int k = j+4;
      W2B[t] = (k<7)? Wr2g[ci*224 + k*32 + c0] : 0.f;
    }
  }
  for (int i=tid;i<1056;i+=256) W1L[i] = Wr1g[i];
  __syncthreads();

  int lane = tid & 63;
  int wv   = tid >> 6;
  int c    = lane & 31;
  int half = lane >> 5;
  int hh   = c >> 3;
  int base = blockIdx.x*64 + wv*16;      // 7500*64 = 480000 exact
  int ll   = lane & 15;
  float b1 = br1g[c];

  // ---- lane-owned edge (ll); lanes 16..31 duplicate 0..15 ----
  int eL = perm[base + ll];
  int sL = src[eL];
  int dL = dst[eL];
  {
    float pdx = pos[dL*3+0]-pos[sL*3+0];
    float pdy = pos[dL*3+1]-pos[sL*3+1];
    float pdz = pos[dL*3+2]-pos[sL*3+2];
    float rr = sqrtf(pdx*pdx+pdy*pdy+pdz*pdz+1e-8f);
    float iv = 1.f/rr;
    if (lane < 16) geoL[wv][ll] = make_float4(rr, pdx*iv, pdy*iv, pdz*iv);
  }

  // ---- prologue gathers for iteration 0 (this half's edges half*4 + 0..3) ----
  int sP[4], dP[4];
  float rvP[4], f0P[4];
  #pragma unroll
  for (int j=0;j<4;j++){
    int idx = half*4 + j;
    int e = __shfl(eL, idx, 32);
    sP[j] = __shfl(sL, idx, 32);
    dP[j] = __shfl(dL, idx, 32);
    rvP[j] = ef[(size_t)e*32 + c];
    f0P[j] = f_in[(size_t)sP[j]*288 + c];
  }

  float A[9];
  #pragma unroll
  for (int j=0;j<9;j++) A[j]=0.f;
  float denA = 0.f;
  int curd = -1;

  #pragma unroll 1
  for (int it=0; it<2; ++it){
    // ---- capture current + commit rv to LDS ----
    int sC[4], dC[4];
    float f0C[4];
    #pragma unroll
    for (int j=0;j<4;j++){
      sC[j]=sP[j]; dC[j]=dP[j]; f0C[j]=f0P[j];
      rvL[wv][half*4+j][c] = rvP[j];
    }

    // ---- on-demand gathers for current edges (consumed after h/w loops) ----
    float T0[4],T1[4],T2[4],T3[4];
    #pragma unroll
    for (int j=0;j<4;j++){
      const float* T = Tq + (size_t)dC[j]*128;
      T0[j]=T[c]; T1[j]=T[32+c]; T2[j]=T[64+c]; T3[j]=T[96+c];
    }
    float f1[4],f2[4],f3[4],f4[4],f5[4],f6[4],f7[4],f8[4];
    #pragma unroll
    for (int j=0;j<4;j++){ f1[j]=0.f;f2[j]=0.f;f3[j]=0.f;f4[j]=0.f;f5[j]=0.f;f6[j]=0.f;f7[j]=0.f;f8[j]=0.f; }
    if (!FIRST){
      #pragma unroll
      for (int j=0;j<4;j++){
        const float* fs = f_in + (size_t)sC[j]*288;
        f1[j]=fs[32+c];  f2[j]=fs[64+c];  f3[j]=fs[96+c];  f4[j]=fs[128+c];
        f5[j]=fs[160+c]; f6[j]=fs[192+c]; f7[j]=fs[224+c]; f8[j]=fs[256+c];
      }
    }

    // ---- branchless prefetch of it+1 (it=1 -> indices 16..23 = dup lanes, valid dummy) ----
    #pragma unroll
    for (int j=0;j<4;j++){
      int idx = (it+1)*8 + half*4 + j;
      int e = __shfl(eL, idx, 32);
      sP[j] = __shfl(sL, idx, 32);
      dP[j] = __shfl(dL, idx, 32);
      rvP[j] = ef[(size_t)e*32 + c];
      f0P[j] = f_in[(size_t)sP[j]*288 + c];
    }

    // ---- geometry (uniform-per-half LDS reads) ----
    float4 g[4];
    #pragma unroll
    for (int j=0;j<4;j++) g[j] = geoL[wv][it*8 + half*4 + j];

    // ---- h for 4 edges (W1 from LDS, rv via uniform float4 LDS reads) ----
    float h0[4],h1[4],h2[4],h3[4];
    #pragma unroll
    for (int j=0;j<4;j++){ h0[j]=fmaf(g[j].x, W1L[c], b1); h1[j]=0.f; h2[j]=0.f; h3[j]=0.f; }
    #pragma unroll
    for (int jb=0;jb<8;jb++){
      float wj0 = W1L[(1+jb*4+0)*32 + c];
      float wj1 = W1L[(1+jb*4+1)*32 + c];
      float wj2 = W1L[(1+jb*4+2)*32 + c];
      float wj3 = W1L[(1+jb*4+3)*32 + c];
      #pragma unroll
      for (int j=0;j<4;j++){
        float4 r = *(const float4*)&rvL[wv][half*4+j][jb*4];
        h0[j] = fmaf(r.x, wj0, h0[j]);
        h1[j] = fmaf(r.y, wj1, h1[j]);
        h2[j] = fmaf(r.z, wj2, h2[j]);
        h3[j] = fmaf(r.w, wj3, h3[j]);
      }
    }
    #pragma unroll
    for (int j=0;j<4;j++){
      float h = fmaxf((h0[j]+h1[j])+(h2[j]+h3[j]), 0.f);
      hL[wv][half*4+j][c] = h;
    }

    // ---- w = h @ W2 for 4 edges; W2 b128 stream shared by all 4 ----
    float w0[4],w1[4],w2[4],w3[4],w4[4],w5[4],w6[4];
    #pragma unroll
    for (int j=0;j<4;j++){ w0[j]=0.f;w1[j]=0.f;w2[j]=0.f;w3[j]=0.f;w4[j]=0.f;w5[j]=0.f;w6[j]=0.f; }
    #pragma unroll
    for (int c4=0;c4<8;c4++){
      float4 hv0 = *(const float4*)&hL[wv][half*4+0][c4*4];
      float4 hv1 = *(const float4*)&hL[wv][half*4+1][c4*4];
      float4 hv2 = *(const float4*)&hL[wv][half*4+2][c4*4];
      float4 hv3 = *(const float4*)&hL[wv][half*4+3][c4*4];
      #pragma unroll
      for (int jj=0;jj<4;jj++){
        int ci = c4*4+jj;
        float hj0 = (jj==0)?hv0.x:((jj==1)?hv0.y:((jj==2)?hv0.z:hv0.w));
        float hj1 = (jj==0)?hv1.x:((jj==1)?hv1.y:((jj==2)?hv1.z:hv1.w));
        float hj2 = (jj==0)?hv2.x:((jj==1)?hv2.y:((jj==2)?hv2.z:hv2.w));
        float hj3 = (jj==0)?hv3.x:((jj==1)?hv3.y:((jj==2)?hv3.z:hv3.w));
        float4 qa = *(const float4*)&W2A[ci*128 + c*4];
        if (FIRST){
          w0[0]=fmaf(hj0,qa.x,w0[0]); w3[0]=fmaf(hj0,qa.y,w3[0]); w5[0]=fmaf(hj0,qa.z,w5[0]);
          w0[1]=fmaf(hj1,qa.x,w0[1]); w3[1]=fmaf(hj1,qa.y,w3[1]); w5[1]=fmaf(hj1,qa.z,w5[1]);
          w0[2]=fmaf(hj2,qa.x,w0[2]); w3[2]=fmaf(hj2,qa.y,w3[2]); w5[2]=fmaf(hj2,qa.z,w5[2]);
          w0[3]=fmaf(hj3,qa.x,w0[3]); w3[3]=fmaf(hj3,qa.y,w3[3]); w5[3]=fmaf(hj3,qa.z,w5[3]);
        } else {
          float4 qb = *(const float4*)&W2B[ci*128 + c*4];
          w0[0]=fmaf(hj0,qa.x,w0[0]); w1[0]=fmaf(hj0,qa.y,w1[0]); w2[0]=fmaf(hj0,qa.z,w2[0]);
          w3[0]=fmaf(hj0,qa.w,w3[0]); w4[0]=fmaf(hj0,qb.x,w4[0]); w5[0]=fmaf(hj0,qb.y,w5[0]);
          w6[0]=fmaf(hj0,qb.z,w6[0]);
          w0[1]=fmaf(hj1,qa.x,w0[1]); w1[1]=fmaf(hj1,qa.y,w1[1]); w2[1]=fmaf(hj1,qa.z,w2[1]);
          w3[1]=fmaf(hj1,qa.w,w3[1]); w4[1]=fmaf(hj1,qb.x,w4[1]); w5[1]=fmaf(hj1,qb.y,w5[1]);
          w6[1]=fmaf(hj1,qb.z,w6[1]);
          w0[2]=fmaf(hj2,qa.x,w0[2]); w1[2]=fmaf(hj2,qa.y,w1[2]); w2[2]=fmaf(hj2,qa.z,w2[2]);
          w3[2]=fmaf(hj2,qa.w,w3[2]); w4[2]=fmaf(hj2,qb.x,w4[2]); w5[2]=fmaf(hj2,qb.y,w5[2]);
          w6[2]=fmaf(hj2,qb.z,w6[2]);
          w0[3]=fmaf(hj3,qa.x,w0[3]); w1[3]=fmaf(hj3,qa.y,w1[3]); w2[3]=fmaf(hj3,qa.z,w2[3]);
          w3[3]=fmaf(hj3,qa.w,w3[3]); w4[3]=fmaf(hj3,qb.x,w4[3]); w5[3]=fmaf(hj3,qb.y,w5[3]);
          w6[3]=fmaf(hj3,qb.z,w6[3]);
        }
      }
    }

    // ---- per-edge: message, logits (red32), exp, segmented accumulate ----
    #pragma unroll
    for (int j=0;j<4;j++){
      float y1x=g[j].y, y1y=g[j].z, y1z=g[j].w;
      float y2a=y1x*y1y, y2b=y1y*y1z, y2c=3.f*y1z*y1z-1.f, y2d=y1x*y1z, y2e=y1x*y1x-y1y*y1y;
      float m0v = w0[j]*f0C[j];
      if (!FIRST){
        m0v += w1[j]*(f1[j]*y1x+f2[j]*y1y+f3[j]*y1z)
             + w2[j]*(f4[j]*y2a+f5[j]*y2b+f6[j]*y2c+f7[j]*y2d+f8[j]*y2e);
      }
      float p0 = red32(m0v*T0[j]);
      float p1 = red32(m0v*T1[j]);
      float p2 = red32(m0v*T2[j]);
      float p3 = red32(m0v*T3[j]);
      float Sh = (hh==0)?p0:((hh==1)?p1:((hh==2)?p2:p3));
      float el = __expf(Sh * 0.35355339059327373f);   // 1/sqrt(8); logits O(1)

      if (dC[j] != curd){
        if (curd >= 0){
          #pragma unroll
          for (int k=0;k<9;k++) atomicAdd(&aggG[(size_t)curd*288 + k*32 + c], A[k]);
          if ((c&7)==0) atomicAdd(&den[(size_t)curd*4 + hh], denA);
        }
        #pragma unroll
        for (int k=0;k<9;k++) A[k]=0.f;
        denA = 0.f;
        curd = dC[j];
      }
      denA += el;
      A[0] = fmaf(el, m0v, A[0]);
      A[1] = fmaf(el, w3[j]*f0C[j]*y1x + w4[j]*f1[j], A[1]);
      A[2] = fmaf(el, w3[j]*f0C[j]*y1y + w4[j]*f2[j], A[2]);
      A[3] = fmaf(el, w3[j]*f0C[j]*y1z + w4[j]*f3[j], A[3]);
      A[4] = fmaf(el, w5[j]*f0C[j]*y2a + w6[j]*f4[j], A[4]);
      A[5] = fmaf(el, w5[j]*f0C[j]*y2b + w6[j]*f5[j], A[5]);
      A[6] = fmaf(el, w5[j]*f0C[j]*y2c + w6[j]*f6[j], A[6]);
      A[7] = fmaf(el, w5[j]*f0C[j]*y2d + w6[j]*f7[j], A[7]);
      A[8] = fmaf(el, w5[j]*f0C[j]*y2e + w6[j]*f8[j], A[8]);
    }
  }
  if (curd >= 0){
    #pragma unroll
    for (int k=0;k<9;k++) atomicAdd(&aggG[(size_t)curd*288 + k*32 + c], A[k]);
    if ((c&7)==0) atomicAdd(&den[(size_t)curd*4 + hh], denA);
  }
}

// ---------- node update ----------
__global__ __launch_bounds__(256) void k_update(
    const float* __restrict__ aggG, const float* __restrict__ f_in,
    const float* __restrict__ den,
    const float* __restrict__ Ws0, const float* __restrict__ Ws1,
    const float* __restrict__ Ws2, const float* __restrict__ Wsk,
    float* __restrict__ f_out)
{
  __shared__ float wL[4096];
  __shared__ float agL[8][297];
  __shared__ float f0L[8][33];
  __shared__ float dL[8][4];
  int tid = threadIdx.x;
  int nb = blockIdx.x*8;
  for (int i=tid;i<1024;i+=256){
    wL[i]=Ws0[i]; wL[1024+i]=Ws1[i]; wL[2048+i]=Ws2[i]; wL[3072+i]=Wsk[i];
  }
  if (tid < 32){
    int nl = tid>>2, hd = tid&3;
    dL[nl][hd] = 1.f/(den[(size_t)(nb+nl)*4 + hd] + 1e-30f);
  }
  { int nl=tid>>5, cc=tid&31; f0L[nl][cc] = f_in[(size_t)(nb+nl)*288 + cc]; }
  __syncthreads();
  for (int i=tid;i<2304;i+=256){
    int nl=i/288, F=i-nl*288, r=F>>5, cc=F&31;
    agL[nl][r*33+cc] = aggG[(size_t)(nb+nl)*288 + F] * dL[nl][cc>>3];
  }
  __syncthreads();
  int nl = tid>>5, o = tid&31;
  size_t obase = (size_t)(nb+nl)*288;
  #pragma unroll 1
  for (int r=0;r<9;r++){
    const float* W = (r==0)? wL : ((r<4)? wL+1024 : wL+2048);
    float acc=0.f;
    #pragma unroll
    for (int cc=0;cc<32;cc++) acc = fmaf(agL[nl][r*33+cc], W[cc*32+o], acc);
    if (r==0){
      #pragma unroll
      for (int cc=0;cc<32;cc++) acc = fmaf(f0L[nl][cc], wL[3072 + cc*32+o], acc);
    }
    f_out[obase + r*32 + o] = acc;
  }
}

// ---------- output head (f32 out) ----------
__global__ __launch_bounds__(256) void k_out(
    const float* __restrict__ f_in, const float* __restrict__ Wout,
    const float* __restrict__ Wc, float* __restrict__ out)
{
  __shared__ float sh[8][33];
  int tid = threadIdx.x;
  int nl = tid>>5, c = tid&31;
  int n = blockIdx.x*8 + nl;
  const float* f0 = f_in + (size_t)n*288;
  float acc=0.f;
  #pragma unroll
  for (int ci=0;ci<32;ci++) acc = fmaf(f0[ci], Wout[ci*32+c], acc);
  out[(size_t)n*32 + c] = acc;
  sh[nl][c] = acc;
  __syncthreads();
  if (tid < 120){
    int nl2 = tid/15, j = tid%15;
    int n2 = blockIdx.x*8 + nl2;
    float a = 0.f;
    #pragma unroll
    for (int ci=0;ci<32;ci++) a = fmaf(sh[nl2][ci], Wc[ci*15+j], a);
    out[(size_t)NN*32 + (size_t)n2*15 + j] = a;
  }
}

extern "C" void kernel_launch(void* const* d_in, const int* in_sizes, int n_in,
                              void* d_out, int out_size, void* d_ws, size_t ws_size,
                              hipStream_t stream)
{
  (void)in_sizes; (void)n_in;
  const float* pos       = (const float*)d_in[0];
  const float* node_l0   = (const float*)d_in[1];
  const float* edge_feat = (const float*)d_in[2];
  const int* esrc = (const int*)d_in[3];
  const int* edst = (const int*)d_in[4];
  const float* Wr1  = (const float*)d_in[5];
  const float* br1  = (const float*)d_in[6];
  const float* Wr2  = (const float*)d_in[7];
  const float* Wq   = (const float*)d_in[8];
  const float* Wk   = (const float*)d_in[9];
  const float* Ws0  = (const float*)d_in[10];
  const float* Ws1  = (const float*)d_in[11];
  const float* Ws2  = (const float*)d_in[12];
  const float* Wsk  = (const float*)d_in[13];
  const float* Wout = (const float*)d_in[14];
  const float* Wc   = (const float*)d_in[15];

  char* ws = (char*)d_ws;
  size_t off = 0;
  auto take = [&](size_t bytes)->char*{
    char* p = ws + off;
    off += (bytes + 255) & ~(size_t)255;
    return p;
  };
  float* fA      = (float*)take((size_t)NN*288*4);
  float* fB      = (float*)take((size_t)NN*288*4);
  float* Tq      = (float*)take((size_t)NN*128*4);
  int*   hist    = (int*)  take((size_t)NN*4);
  int*   offs    = (int*)  take((size_t)(NN+1)*4);
  int*   cursor  = (int*)  take((size_t)NN*4);
  int*   perm    = (int*)  take((size_t)EE*4);
  float* den     = (float*)take((size_t)NN*4*4);
  size_t need = off;                                  // ~88 MB

  if (ws_size < need){
    k_zero<<<(out_size+255)/256,256,0,stream>>>((float*)d_out, out_size);
    return;
  }

  k_init<<<33750,256,0,stream>>>(node_l0, fA, hist);
  k_hist<<<1875,256,0,stream>>>(edst, hist);
  k_scan<<<1,1024,0,stream>>>(hist, offs, cursor, NN);
  k_scatter<<<1875,256,0,stream>>>(edst, cursor, perm);

  float* fi = fA; float* fo = fB;
  for (int l=0; l<2; ++l){
    k_zeroagg<<<33750,256,0,stream>>>(fo, den);
    k_qt<<<3750,256,0,stream>>>(fi, Wq + l*1024, Wk + l*1024, Tq);
    if (l==0){
      k_fused<1><<<7500,256,0,stream>>>(pos, edge_feat, esrc, edst, perm,
          fi, Tq, Wr1 + l*1056, br1 + l*32, Wr2 + l*7168,
          fo, den);
    } else {
      k_fused<0><<<7500,256,0,stream>>>(pos, edge_feat, esrc, edst, perm,
          fi, Tq, Wr1 + l*1056, br1 + l*32, Wr2 + l*7168,
          fo, den);
    }
    k_update<<<3750,256,0,stream>>>(fo, fi, den,
        Ws0 + l*1024, Ws1 + l*1024, Ws2 + l*1024, Wsk + l*1024, fo);
    float* tmp = fi; fi = fo; fo = tmp;
  }
  k_out<<<3750,256,0,stream>>>(fi, Wout, Wc, (float*)d_out);
}

// Round 9
// 1422.283 us; speedup vs baseline: 3.6005x; 1.5219x over previous
//
#include <hip/hip_runtime.h>

#define NN 30000
#define EE 480000

// ---------- zero-fill fallback (ws too small diagnostic) ----------
__global__ __launch_bounds__(256) void k_zero(float* __restrict__ out, int n){
  int i = blockIdx.x*256 + threadIdx.x;
  if (i < n) out[i] = 0.f;
}

// ---------- node feature init: fA[N][288] (row0=node_l0, rest 0), hist=0 ----------
__global__ __launch_bounds__(256) void k_init(
    const float* __restrict__ nl0, float* __restrict__ fA, int* __restrict__ hist)
{
  int i = blockIdx.x*256 + threadIdx.x;   // exactly N*288
  int n = i/288; int r2 = i - n*288;
  fA[i] = (r2 < 32) ? nl0[(size_t)n*32 + r2] : 0.f;
  if (i < NN) hist[i] = 0;
}

__global__ __launch_bounds__(256) void k_hist(const int* __restrict__ dst, int* __restrict__ hist){
  int e = blockIdx.x*256 + threadIdx.x;
  if (e < EE) atomicAdd(&hist[dst[e]], 1);
}

// single-block exclusive scan over hist[NN] -> offs, cursor
__global__ void k_scan(const int* __restrict__ hist, int* __restrict__ offs,
                       int* __restrict__ cursor, int n)
{
  __shared__ int sm[1024];
  __shared__ int carry;
  int tid = threadIdx.x;
  if (tid==0) carry = 0;
  __syncthreads();
  for (int base=0; base<n; base+=1024){
    int i = base + tid;
    int v = (i<n)? hist[i] : 0;
    sm[tid] = v; __syncthreads();
    for (int o=1;o<1024;o<<=1){
      int tv = (tid>=o)? sm[tid-o] : 0;
      __syncthreads();
      sm[tid] += tv;
      __syncthreads();
    }
    int cy = carry;
    int excl = sm[tid] - v;
    if (i<n){ offs[i] = cy+excl; cursor[i] = cy+excl; }
    __syncthreads();
    if (tid==1023) carry = cy + sm[1023];
    __syncthreads();
  }
  if (tid==0) offs[n] = carry;
}

__global__ __launch_bounds__(256) void k_scatter(const int* __restrict__ dst,
    int* __restrict__ cursor, int* __restrict__ perm)
{
  int e = blockIdx.x*256 + threadIdx.x;
  if (e >= EE) return;
  int d = dst[e];
  int p = atomicAdd(&cursor[d], 1);
  perm[p] = e;
}

// ---------- per-node q projection folded into T ----------
__global__ __launch_bounds__(256) void k_qt(
    const float* __restrict__ f_in, const float* __restrict__ Wqf,
    const float* __restrict__ Wkf, float* __restrict__ Tq)
{
  __shared__ float WqL[1024];
  __shared__ float WkL[1056];           // [c][33] padded
  int tid = threadIdx.x;
  for (int i=tid;i<1024;i+=256) WqL[i]=Wqf[i];
  for (int i=tid;i<1056;i+=256){ int r=i/33, o=i-r*33; if (o<32) WkL[i]=Wkf[r*32+o]; }
  __syncthreads();
  int n = blockIdx.x*8 + (tid>>5), c = tid&31;
  const float* f0 = f_in + (size_t)n*288;
  float q=0.f;
  #pragma unroll
  for (int ci=0;ci<32;ci++) q = fmaf(f0[ci], WqL[ci*32+c], q);
  float t0=0.f,t1=0.f,t2=0.f,t3=0.f;
  #pragma unroll
  for (int j=0;j<32;j++){
    float qb = __shfl(q, j, 32);
    float wv = WkL[c*33 + j];
    if (j<8)       t0 = fmaf(wv, qb, t0);
    else if (j<16) t1 = fmaf(wv, qb, t1);
    else if (j<24) t2 = fmaf(wv, qb, t2);
    else           t3 = fmaf(wv, qb, t3);
  }
  float* T = Tq + (size_t)n*128;
  T[c]=t0; T[32+c]=t1; T[64+c]=t2; T[96+c]=t3;
}

// ---------- zero agg buffer + den ----------
__global__ __launch_bounds__(256) void k_zeroagg(float* __restrict__ fo, float* __restrict__ den){
  int i = blockIdx.x*256 + threadIdx.x;
  fo[i] = 0.f;
  if (i < NN*4) den[i] = 0.f;
}

// DPP reduction: x += partner (involutive perms), VALU pipe. HW-proven (R7/R8 passed).
template<int CTRL>
__device__ __forceinline__ float dpp_add(float x){
  return x + __int_as_float(__builtin_amdgcn_mov_dpp(__float_as_int(x), CTRL, 0xF, 0xF, true));
}
__device__ __forceinline__ float red32(float p){
  p = dpp_add<0xB1>(p);    // quad xor1
  p = dpp_add<0x4E>(p);    // quad xor2
  p = dpp_add<0x141>(p);   // row_half_mirror (pairs quads within 8)
  p = dpp_add<0x140>(p);   // row_mirror (pairs 8-groups within 16)
  p += __shfl_xor(p, 16, 32);
  return p;
}

// ---------- fused edge pass: R6 structure + cross-iteration H/W software pipeline ----------
// 16 edges/wave (lane-owned hoist), 4 edges/iteration. The R6 same-iteration LDS
// chain (rv write -> h read -> hL write -> w read) is split across iterations:
// body(it) = {commit rv(it+1); prefetch f/T(it+1)+rv(it+2); W-phase(it) on
// hL[it&1]; H-phase(it+1) -> hL[(it+1)&1]}. Every LDS write->read pair is
// separated by >=1 full phase. rvL/hL parity double-buffered (LDS, 0 regs).
// Plain launch_bounds(256): NEVER force occupancy (R7); pipeline state kept at
// R6's scalar set (R8's 8-edge variant hit VGPR 256 + spill).
template<int FIRST>
__global__ __launch_bounds__(256) void k_fused(
    const float* __restrict__ pos, const float* __restrict__ ef,
    const int* __restrict__ src, const int* __restrict__ dst,
    const int* __restrict__ perm,
    const float* __restrict__ f_in, const float* __restrict__ Tq,
    const float* __restrict__ Wr1g, const float* __restrict__ br1g,
    const float* __restrict__ Wr2g,
    float* __restrict__ aggG, float* __restrict__ den)
{
  __shared__ __align__(16) float W2A[4096];
  __shared__ __align__(16) float W2B[FIRST ? 4 : 4096];
  __shared__ __align__(16) float rvL[4][2][4][32];   // [wave][parity][edge][ch]
  __shared__ __align__(16) float hL [4][2][4][32];
  __shared__ float4 geoL[4][16];
  int tid = threadIdx.x;
  if (FIRST){
    for (int t=tid;t<4096;t+=256){
      int ci=t>>7, r=t&127, c0=r>>2, j=r&3;
      int k = (j==0)?0:((j==1)?3:((j==2)?5:-1));
      W2A[t] = (k>=0)? Wr2g[ci*224 + k*32 + c0] : 0.f;
    }
  } else {
    for (int t=tid;t<4096;t+=256){
      int ci=t>>7, r=t&127, c0=r>>2, j=r&3;
      W2A[t] = Wr2g[ci*224 + j*32 + c0];
      int k = j+4;
      W2B[t] = (k<7)? Wr2g[ci*224 + k*32 + c0] : 0.f;
    }
  }
  __syncthreads();

  int lane = tid & 63;
  int wv   = tid >> 6;
  int c    = lane & 31;
  int half = lane >> 5;
  int hh   = c >> 3;
  int base = blockIdx.x*64 + wv*16;      // 7500*64 = 480000 exact
  int ll   = lane & 15;

  // W1 column in registers (zero DS on weight side of h-loop)
  float w1r[33];
  #pragma unroll
  for (int j=0;j<33;j++) w1r[j] = Wr1g[j*32 + c];
  float b1 = br1g[c];

  // ---- lane-owned edge (ll); lanes 16..31 duplicate 0..15 ----
  int eL = perm[base + ll];
  int sL = src[eL];
  int dL = dst[eL];
  {
    float pdx = pos[dL*3+0]-pos[sL*3+0];
    float pdy = pos[dL*3+1]-pos[sL*3+1];
    float pdz = pos[dL*3+2]-pos[sL*3+2];
    float rr = sqrtf(pdx*pdx+pdy*pdy+pdz*pdz+1e-8f);
    float iv = 1.f/rr;
    if (lane < 16) geoL[wv][ll] = make_float4(rr, pdx*iv, pdy*iv, pdz*iv);
  }

  // ---- prologue ----
  // X0: it=0 rv -> rvL[0]; f/T(0) -> P regs
  int dPa, dPb;
  float faP0,faP1=0.f,faP2=0.f,faP3=0.f,faP4=0.f,faP5=0.f,faP6=0.f,faP7=0.f,faP8=0.f;
  float fbP0,fbP1=0.f,fbP2=0.f,fbP3=0.f,fbP4=0.f,fbP5=0.f,fbP6=0.f,fbP7=0.f,fbP8=0.f;
  float TPa0,TPa1,TPa2,TPa3, TPb0,TPb1,TPb2,TPb3;
  {
    int i0 = 2*half, i1 = i0+1;
    int eA = __shfl(eL, i0, 32);
    int eB = __shfl(eL, i1, 32);
    int sA = __shfl(sL, i0, 32);
    int sB = __shfl(sL, i1, 32);
    dPa = __shfl(dL, i0, 32);
    dPb = __shfl(dL, i1, 32);
    float r0 = ef[(size_t)eA*32 + c];
    float r1 = ef[(size_t)eB*32 + c];
    rvL[wv][0][half*2+0][c] = r0;
    rvL[wv][0][half*2+1][c] = r1;
    const float* fsA = f_in + (size_t)sA*288;
    const float* fsB = f_in + (size_t)sB*288;
    faP0 = fsA[c]; fbP0 = fsB[c];
    if (!FIRST){
      faP1=fsA[32+c]; faP2=fsA[64+c]; faP3=fsA[96+c]; faP4=fsA[128+c];
      faP5=fsA[160+c]; faP6=fsA[192+c]; faP7=fsA[224+c]; faP8=fsA[256+c];
      fbP1=fsB[32+c]; fbP2=fsB[64+c]; fbP3=fsB[96+c]; fbP4=fsB[128+c];
      fbP5=fsB[160+c]; fbP6=fsB[192+c]; fbP7=fsB[224+c]; fbP8=fsB[256+c];
    }
    const float* TA = Tq + (size_t)dPa*128;
    const float* TB = Tq + (size_t)dPb*128;
    TPa0=TA[c]; TPa1=TA[32+c]; TPa2=TA[64+c]; TPa3=TA[96+c];
    TPb0=TB[c]; TPb1=TB[32+c]; TPb2=TB[64+c]; TPb3=TB[96+c];
  }
  // H0: h(0) -> hL[0]
  {
    float4 gA = geoL[wv][2*half];
    float4 gB = geoL[wv][2*half+1];
    float ha0 = fmaf(gA.x, w1r[0], b1), ha1=0.f, ha2=0.f, ha3=0.f;
    float hb0 = fmaf(gB.x, w1r[0], b1), hb1=0.f, hb2=0.f, hb3=0.f;
    #pragma unroll
    for (int jb=0;jb<8;jb++){
      float4 ra = *(const float4*)&rvL[wv][0][half*2+0][jb*4];
      float4 rb = *(const float4*)&rvL[wv][0][half*2+1][jb*4];
      ha0 = fmaf(ra.x, w1r[1+jb*4+0], ha0);
      ha1 = fmaf(ra.y, w1r[1+jb*4+1], ha1);
      ha2 = fmaf(ra.z, w1r[1+jb*4+2], ha2);
      ha3 = fmaf(ra.w, w1r[1+jb*4+3], ha3);
      hb0 = fmaf(rb.x, w1r[1+jb*4+0], hb0);
      hb1 = fmaf(rb.y, w1r[1+jb*4+1], hb1);
      hb2 = fmaf(rb.z, w1r[1+jb*4+2], hb2);
      hb3 = fmaf(rb.w, w1r[1+jb*4+3], hb3);
    }
    hL[wv][0][half*2+0][c] = fmaxf((ha0+ha1)+(ha2+ha3), 0.f);
    hL[wv][0][half*2+1][c] = fmaxf((hb0+hb1)+(hb2+hb3), 0.f);
  }
  // X1: rv(1) -> regs
  float rvPa, rvPb;
  {
    int i0 = 4 + 2*half, i1 = i0+1;
    int eA = __shfl(eL, i0, 32);
    int eB = __shfl(eL, i1, 32);
    rvPa = ef[(size_t)eA*32 + c];
    rvPb = ef[(size_t)eB*32 + c];
  }

  float A[9];
  #pragma unroll
  for (int j=0;j<9;j++) A[j]=0.f;
  float denA = 0.f;
  int curd = -1;

  #pragma unroll 1
  for (int it=0; it<4; ++it){
    int p0 = it&1, p1 = p0^1;
    // ---- capture current (it) ----
    int dCa=dPa, dCb=dPb;
    float fa0=faP0,fa1=faP1,fa2=faP2,fa3=faP3,fa4=faP4,fa5=faP5,fa6=faP6,fa7=faP7,fa8=faP8;
    float fb0=fbP0,fb1=fbP1,fb2=fbP2,fb3=fbP3,fb4=fbP4,fb5=fbP5,fb6=fbP6,fb7=fbP7,fb8=fbP8;
    float Sa0=TPa0,Sa1=TPa1,Sa2=TPa2,Sa3=TPa3;
    float Sb0=TPb0,Sb1=TPb1,Sb2=TPb2,Sb3=TPb3;

    if (it < 3){
      // commit rv(it+1) (loaded last body) -- consumed by H-phase AFTER W-phase
      rvL[wv][p1][half*2+0][c] = rvPa;
      rvL[wv][p1][half*2+1][c] = rvPb;
      // prefetch indices for it+1 (f/T) and it+2 (rv)
      int ia = (it+1)*4 + 2*half, ib = ia+1;
      int sA = __shfl(sL, ia, 32);
      int sB = __shfl(sL, ib, 32);
      dPa = __shfl(dL, ia, 32);
      dPb = __shfl(dL, ib, 32);
      const float* fsA = f_in + (size_t)sA*288;
      const float* fsB = f_in + (size_t)sB*288;
      faP0 = fsA[c]; fbP0 = fsB[c];
      if (!FIRST){
        faP1=fsA[32+c]; faP2=fsA[64+c]; faP3=fsA[96+c]; faP4=fsA[128+c];
        faP5=fsA[160+c]; faP6=fsA[192+c]; faP7=fsA[224+c]; faP8=fsA[256+c];
        fbP1=fsB[32+c]; fbP2=fsB[64+c]; fbP3=fsB[96+c]; fbP4=fsB[128+c];
        fbP5=fsB[160+c]; fbP6=fsB[192+c]; fbP7=fsB[224+c]; fbP8=fsB[256+c];
      }
      const float* TA = Tq + (size_t)dPa*128;
      const float* TB = Tq + (size_t)dPb*128;
      TPa0=TA[c]; TPa1=TA[32+c]; TPa2=TA[64+c]; TPa3=TA[96+c];
      TPb0=TB[c]; TPb1=TB[32+c]; TPb2=TB[64+c]; TPb3=TB[96+c];
      int ja = (it+2)*4 + 2*half, jb2 = ja+1;   // max 23 -> dup lanes, valid
      int eA2 = __shfl(eL, ja, 32);
      int eB2 = __shfl(eL, jb2, 32);
      rvPa = ef[(size_t)eA2*32 + c];
      rvPb = ef[(size_t)eB2*32 + c];
    }

    // ---- W-phase(it): w-loop on hL[p0] + messages + logits + accumulate ----
    float4 ga = geoL[wv][it*4 + 2*half];
    float4 gb = geoL[wv][it*4 + 2*half + 1];

    float wa0=0.f,wa1=0.f,wa2=0.f,wa3=0.f,wa4=0.f,wa5=0.f,wa6=0.f;
    float wb0=0.f,wb1=0.f,wb2=0.f,wb3=0.f,wb4=0.f,wb5=0.f,wb6=0.f;
    #pragma unroll
    for (int c4=0;c4<8;c4++){
      float4 ha4 = *(const float4*)&hL[wv][p0][half*2+0][c4*4];
      float4 hb4 = *(const float4*)&hL[wv][p0][half*2+1][c4*4];
      #pragma unroll
      for (int j=0;j<4;j++){
        int ci = c4*4+j;
        float haj = (j==0)?ha4.x:((j==1)?ha4.y:((j==2)?ha4.z:ha4.w));
        float hbj = (j==0)?hb4.x:((j==1)?hb4.y:((j==2)?hb4.z:hb4.w));
        float4 qa = *(const float4*)&W2A[ci*128 + c*4];
        if (FIRST){
          wa0 = fmaf(haj, qa.x, wa0); wa3 = fmaf(haj, qa.y, wa3); wa5 = fmaf(haj, qa.z, wa5);
          wb0 = fmaf(hbj, qa.x, wb0); wb3 = fmaf(hbj, qa.y, wb3); wb5 = fmaf(hbj, qa.z, wb5);
        } else {
          float4 qb = *(const float4*)&W2B[ci*128 + c*4];
          wa0 = fmaf(haj, qa.x, wa0); wa1 = fmaf(haj, qa.y, wa1);
          wa2 = fmaf(haj, qa.z, wa2); wa3 = fmaf(haj, qa.w, wa3);
          wa4 = fmaf(haj, qb.x, wa4); wa5 = fmaf(haj, qb.y, wa5);
          wa6 = fmaf(haj, qb.z, wa6);
          wb0 = fmaf(hbj, qa.x, wb0); wb1 = fmaf(hbj, qa.y, wb1);
          wb2 = fmaf(hbj, qa.z, wb2); wb3 = fmaf(hbj, qa.w, wb3);
          wb4 = fmaf(hbj, qb.x, wb4); wb5 = fmaf(hbj, qb.y, wb5);
          wb6 = fmaf(hbj, qb.z, wb6);
        }
      }
    }

    float y2aA=ga.y*ga.z, y2bA=ga.z*ga.w, y2cA=3.f*ga.w*ga.w-1.f, y2dA=ga.y*ga.w, y2eA=ga.y*ga.y-ga.z*ga.z;
    float y2aB=gb.y*gb.z, y2bB=gb.z*gb.w, y2cB=3.f*gb.w*gb.w-1.f, y2dB=gb.y*gb.w, y2eB=gb.y*gb.y-gb.z*gb.z;
    float m0A = wa0*fa0;
    float m0B = wb0*fb0;
    if (!FIRST){
      m0A += wa1*(fa1*ga.y+fa2*ga.z+fa3*ga.w)
           + wa2*(fa4*y2aA+fa5*y2bA+fa6*y2cA+fa7*y2dA+fa8*y2eA);
      m0B += wb1*(fb1*gb.y+fb2*gb.z+fb3*gb.w)
           + wb2*(fb4*y2aB+fb5*y2bB+fb6*y2cB+fb7*y2dB+fb8*y2eB);
    }

    float pa0 = red32(m0A*Sa0), pa1 = red32(m0A*Sa1);
    float pa2 = red32(m0A*Sa2), pa3 = red32(m0A*Sa3);
    float pb0 = red32(m0B*Sb0), pb1 = red32(m0B*Sb1);
    float pb2 = red32(m0B*Sb2), pb3 = red32(m0B*Sb3);
    float ShA = (hh==0)?pa0:((hh==1)?pa1:((hh==2)?pa2:pa3));
    float ShB = (hh==0)?pb0:((hh==1)?pb1:((hh==2)?pb2:pb3));
    float elA = __expf(ShA * 0.35355339059327373f);   // 1/sqrt(8); logits O(1)
    float elB = __expf(ShB * 0.35355339059327373f);

    if (dCa != curd){
      if (curd >= 0){
        #pragma unroll
        for (int j=0;j<9;j++) atomicAdd(&aggG[(size_t)curd*288 + j*32 + c], A[j]);
        if ((c&7)==0) atomicAdd(&den[(size_t)curd*4 + hh], denA);
      }
      #pragma unroll
      for (int j=0;j<9;j++) A[j]=0.f;
      denA = 0.f;
      curd = dCa;
    }
    denA += elA;
    A[0] = fmaf(elA, m0A, A[0]);
    A[1] = fmaf(elA, wa3*fa0*ga.y + wa4*fa1, A[1]);
    A[2] = fmaf(elA, wa3*fa0*ga.z + wa4*fa2, A[2]);
    A[3] = fmaf(elA, wa3*fa0*ga.w + wa4*fa3, A[3]);
    A[4] = fmaf(elA, wa5*fa0*y2aA + wa6*fa4, A[4]);
    A[5] = fmaf(elA, wa5*fa0*y2bA + wa6*fa5, A[5]);
    A[6] = fmaf(elA, wa5*fa0*y2cA + wa6*fa6, A[6]);
    A[7] = fmaf(elA, wa5*fa0*y2dA + wa6*fa7, A[7]);
    A[8] = fmaf(elA, wa5*fa0*y2eA + wa6*fa8, A[8]);

    if (dCb != curd){
      if (curd >= 0){
        #pragma unroll
        for (int j=0;j<9;j++) atomicAdd(&aggG[(size_t)curd*288 + j*32 + c], A[j]);
        if ((c&7)==0) atomicAdd(&den[(size_t)curd*4 + hh], denA);
      }
      #pragma unroll
      for (int j=0;j<9;j++) A[j]=0.f;
      denA = 0.f;
      curd = dCb;
    }
    denA += elB;
    A[0] = fmaf(elB, m0B, A[0]);
    A[1] = fmaf(elB, wb3*fb0*gb.y + wb4*fb1, A[1]);
    A[2] = fmaf(elB, wb3*fb0*gb.z + wb4*fb2, A[2]);
    A[3] = fmaf(elB, wb3*fb0*gb.w + wb4*fb3, A[3]);
    A[4] = fmaf(elB, wb5*fb0*y2aB + wb6*fb4, A[4]);
    A[5] = fmaf(elB, wb5*fb0*y2bB + wb6*fb5, A[5]);
    A[6] = fmaf(elB, wb5*fb0*y2cB + wb6*fb6, A[6]);
    A[7] = fmaf(elB, wb5*fb0*y2dB + wb6*fb7, A[7]);
    A[8] = fmaf(elB, wb5*fb0*y2eB + wb6*fb8, A[8]);

    // ---- H-phase(it+1): h-loop on rvL[p1] (committed at top of THIS body) ----
    if (it < 3){
      float4 gA2 = geoL[wv][(it+1)*4 + 2*half];
      float4 gB2 = geoL[wv][(it+1)*4 + 2*half + 1];
      float ha0 = fmaf(gA2.x, w1r[0], b1), ha1=0.f, ha2=0.f, ha3=0.f;
      float hb0 = fmaf(gB2.x, w1r[0], b1), hb1=0.f, hb2=0.f, hb3=0.f;
      #pragma unroll
      for (int jb=0;jb<8;jb++){
        float4 ra = *(const float4*)&rvL[wv][p1][half*2+0][jb*4];
        float4 rb = *(const float4*)&rvL[wv][p1][half*2+1][jb*4];
        ha0 = fmaf(ra.x, w1r[1+jb*4+0], ha0);
        ha1 = fmaf(ra.y, w1r[1+jb*4+1], ha1);
        ha2 = fmaf(ra.z, w1r[1+jb*4+2], ha2);
        ha3 = fmaf(ra.w, w1r[1+jb*4+3], ha3);
        hb0 = fmaf(rb.x, w1r[1+jb*4+0], hb0);
        hb1 = fmaf(rb.y, w1r[1+jb*4+1], hb1);
        hb2 = fmaf(rb.z, w1r[1+jb*4+2], hb2);
        hb3 = fmaf(rb.w, w1r[1+jb*4+3], hb3);
      }
      hL[wv][p1][half*2+0][c] = fmaxf((ha0+ha1)+(ha2+ha3), 0.f);
      hL[wv][p1][half*2+1][c] = fmaxf((hb0+hb1)+(hb2+hb3), 0.f);
    }
  }
  if (curd >= 0){
    #pragma unroll
    for (int j=0;j<9;j++) atomicAdd(&aggG[(size_t)curd*288 + j*32 + c], A[j]);
    if ((c&7)==0) atomicAdd(&den[(size_t)curd*4 + hh], denA);
  }
}

// ---------- node update ----------
__global__ __launch_bounds__(256) void k_update(
    const float* __restrict__ aggG, const float* __restrict__ f_in,
    const float* __restrict__ den,
    const float* __restrict__ Ws0, const float* __restrict__ Ws1,
    const float* __restrict__ Ws2, const float* __restrict__ Wsk,
    float* __restrict__ f_out)
{
  __shared__ float wL[4096];
  __shared__ float agL[8][297];
  __shared__ float f0L[8][33];
  __shared__ float dL[8][4];
  int tid = threadIdx.x;
  int nb = blockIdx.x*8;
  for (int i=tid;i<1024;i+=256){
    wL[i]=Ws0[i]; wL[1024+i]=Ws1[i]; wL[2048+i]=Ws2[i]; wL[3072+i]=Wsk[i];
  }
  if (tid < 32){
    int nl = tid>>2, hd = tid&3;
    dL[nl][hd] = 1.f/(den[(size_t)(nb+nl)*4 + hd] + 1e-30f);
  }
  { int nl=tid>>5, cc=tid&31; f0L[nl][cc] = f_in[(size_t)(nb+nl)*288 + cc]; }
  __syncthreads();
  for (int i=tid;i<2304;i+=256){
    int nl=i/288, F=i-nl*288, r=F>>5, cc=F&31;
    agL[nl][r*33+cc] = aggG[(size_t)(nb+nl)*288 + F] * dL[nl][cc>>3];
  }
  __syncthreads();
  int nl = tid>>5, o = tid&31;
  size_t obase = (size_t)(nb+nl)*288;
  #pragma unroll 1
  for (int r=0;r<9;r++){
    const float* W = (r==0)? wL : ((r<4)? wL+1024 : wL+2048);
    float acc=0.f;
    #pragma unroll
    for (int cc=0;cc<32;cc++) acc = fmaf(agL[nl][r*33+cc], W[cc*32+o], acc);
    if (r==0){
      #pragma unroll
      for (int cc=0;cc<32;cc++) acc = fmaf(f0L[nl][cc], wL[3072 + cc*32+o], acc);
    }
    f_out[obase + r*32 + o] = acc;
  }
}

// ---------- output head (f32 out) ----------
__global__ __launch_bounds__(256) void k_out(
    const float* __restrict__ f_in, const float* __restrict__ Wout,
    const float* __restrict__ Wc, float* __restrict__ out)
{
  __shared__ float sh[8][33];
  int tid = threadIdx.x;
  int nl = tid>>5, c = tid&31;
  int n = blockIdx.x*8 + nl;
  const float* f0 = f_in + (size_t)n*288;
  float acc=0.f;
  #pragma unroll
  for (int ci=0;ci<32;ci++) acc = fmaf(f0[ci], Wout[ci*32+c], acc);
  out[(size_t)n*32 + c] = acc;
  sh[nl][c] = acc;
  __syncthreads();
  if (tid < 120){
    int nl2 = tid/15, j = tid%15;
    int n2 = blockIdx.x*8 + nl2;
    float a = 0.f;
    #pragma unroll
    for (int ci=0;ci<32;ci++) a = fmaf(sh[nl2][ci], Wc[ci*15+j], a);
    out[(size_t)NN*32 + (size_t)n2*15 + j] = a;
  }
}

extern "C" void kernel_launch(void* const* d_in, const int* in_sizes, int n_in,
                              void* d_out, int out_size, void* d_ws, size_t ws_size,
                              hipStream_t stream)
{
  (void)in_sizes; (void)n_in;
  const float* pos       = (const float*)d_in[0];
  const float* node_l0   = (const float*)d_in[1];
  const float* edge_feat = (const float*)d_in[2];
  const int* esrc = (const int*)d_in[3];
  const int* edst = (const int*)d_in[4];
  const float* Wr1  = (const float*)d_in[5];
  const float* br1  = (const float*)d_in[6];
  const float* Wr2  = (const float*)d_in[7];
  const float* Wq   = (const float*)d_in[8];
  const float* Wk   = (const float*)d_in[9];
  const float* Ws0  = (const float*)d_in[10];
  const float* Ws1  = (const float*)d_in[11];
  const float* Ws2  = (const float*)d_in[12];
  const float* Wsk  = (const float*)d_in[13];
  const float* Wout = (const float*)d_in[14];
  const float* Wc   = (const float*)d_in[15];

  char* ws = (char*)d_ws;
  size_t off = 0;
  auto take = [&](size_t bytes)->char*{
    char* p = ws + off;
    off += (bytes + 255) & ~(size_t)255;
    return p;
  };
  float* fA      = (float*)take((size_t)NN*288*4);
  float* fB      = (float*)take((size_t)NN*288*4);
  float* Tq      = (float*)take((size_t)NN*128*4);
  int*   hist    = (int*)  take((size_t)NN*4);
  int*   offs    = (int*)  take((size_t)(NN+1)*4);
  int*   cursor  = (int*)  take((size_t)NN*4);
  int*   perm    = (int*)  take((size_t)EE*4);
  float* den     = (float*)take((size_t)NN*4*4);
  size_t need = off;                                  // ~88 MB

  if (ws_size < need){
    k_zero<<<(out_size+255)/256,256,0,stream>>>((float*)d_out, out_size);
    return;
  }

  k_init<<<33750,256,0,stream>>>(node_l0, fA, hist);
  k_hist<<<1875,256,0,stream>>>(edst, hist);
  k_scan<<<1,1024,0,stream>>>(hist, offs, cursor, NN);
  k_scatter<<<1875,256,0,stream>>>(edst, cursor, perm);

  float* fi = fA; float* fo = fB;
  for (int l=0; l<2; ++l){
    k_zeroagg<<<33750,256,0,stream>>>(fo, den);
    k_qt<<<3750,256,0,stream>>>(fi, Wq + l*1024, Wk + l*1024, Tq);
    if (l==0){
      k_fused<1><<<7500,256,0,stream>>>(pos, edge_feat, esrc, edst, perm,
          fi, Tq, Wr1 + l*1056, br1 + l*32, Wr2 + l*7168,
          fo, den);
    } else {
      k_fused<0><<<7500,256,0,stream>>>(pos, edge_feat, esrc, edst, perm,
          fi, Tq, Wr1 + l*1056, br1 + l*32, Wr2 + l*7168,
          fo, den);
    }
    k_update<<<3750,256,0,stream>>>(fo, fi, den,
        Ws0 + l*1024, Ws1 + l*1024, Ws2 + l*1024, Wsk + l*1024, fo);
    float* tmp = fi; fi = fo; fo = tmp;
  }
  k_out<<<3750,256,0,stream>>>(fi, Wout, Wc, (float*)d_out);
}

// Round 10
// 1272.678 us; speedup vs baseline: 4.0238x; 1.1176x over previous
//
#include <hip/hip_runtime.h>

#define NN 30000
#define EE 480000

// Feature row layout (288 floats/node, SAME footprint as before):
//   [0..31]   f0, channel-dense (k_init/k_qt/k_out read unchanged)
//   [32..287] f1..f8 channel-major: offset 32 + c*8 + (j-1)  -> two aligned
//             float4 loads per (edge,channel) instead of 8 scalar loads.
// Agg accumulation in the SAME buffer uses the old [j][32] layout (j*32+c);
// k_update converts agg-layout -> feature-layout in place (block-local, synced).
// Tq layout: [n][32][4] -> one float4 per (edge,channel).

// ---------- zero-fill fallback (ws too small diagnostic) ----------
__global__ __launch_bounds__(256) void k_zero(float* __restrict__ out, int n){
  int i = blockIdx.x*256 + threadIdx.x;
  if (i < n) out[i] = 0.f;
}

// ---------- node feature init: fA[N][288] (f0=node_l0, rest 0), hist=0 ----------
__global__ __launch_bounds__(256) void k_init(
    const float* __restrict__ nl0, float* __restrict__ fA, int* __restrict__ hist)
{
  int i = blockIdx.x*256 + threadIdx.x;   // exactly N*288
  int n = i/288; int r2 = i - n*288;
  fA[i] = (r2 < 32) ? nl0[(size_t)n*32 + r2] : 0.f;   // zeros valid in any layout
  if (i < NN) hist[i] = 0;
}

__global__ __launch_bounds__(256) void k_hist(const int* __restrict__ dst, int* __restrict__ hist){
  int e = blockIdx.x*256 + threadIdx.x;
  if (e < EE) atomicAdd(&hist[dst[e]], 1);
}

// single-block exclusive scan over hist[NN] -> offs, cursor
__global__ void k_scan(const int* __restrict__ hist, int* __restrict__ offs,
                       int* __restrict__ cursor, int n)
{
  __shared__ int sm[1024];
  __shared__ int carry;
  int tid = threadIdx.x;
  if (tid==0) carry = 0;
  __syncthreads();
  for (int base=0; base<n; base+=1024){
    int i = base + tid;
    int v = (i<n)? hist[i] : 0;
    sm[tid] = v; __syncthreads();
    for (int o=1;o<1024;o<<=1){
      int tv = (tid>=o)? sm[tid-o] : 0;
      __syncthreads();
      sm[tid] += tv;
      __syncthreads();
    }
    int cy = carry;
    int excl = sm[tid] - v;
    if (i<n){ offs[i] = cy+excl; cursor[i] = cy+excl; }
    __syncthreads();
    if (tid==1023) carry = cy + sm[1023];
    __syncthreads();
  }
  if (tid==0) offs[n] = carry;
}

__global__ __launch_bounds__(256) void k_scatter(const int* __restrict__ dst,
    int* __restrict__ cursor, int* __restrict__ perm)
{
  int e = blockIdx.x*256 + threadIdx.x;
  if (e >= EE) return;
  int d = dst[e];
  int p = atomicAdd(&cursor[d], 1);
  perm[p] = e;
}

// ---------- per-node q projection folded into T; Tq stored [n][32][4] ----------
__global__ __launch_bounds__(256) void k_qt(
    const float* __restrict__ f_in, const float* __restrict__ Wqf,
    const float* __restrict__ Wkf, float* __restrict__ Tq)
{
  __shared__ float WqL[1024];
  __shared__ float WkL[1056];           // [c][33] padded
  int tid = threadIdx.x;
  for (int i=tid;i<1024;i+=256) WqL[i]=Wqf[i];
  for (int i=tid;i<1056;i+=256){ int r=i/33, o=i-r*33; if (o<32) WkL[i]=Wkf[r*32+o]; }
  __syncthreads();
  int n = blockIdx.x*8 + (tid>>5), c = tid&31;
  const float* f0 = f_in + (size_t)n*288;
  float q=0.f;
  #pragma unroll
  for (int ci=0;ci<32;ci++) q = fmaf(f0[ci], WqL[ci*32+c], q);
  float t0=0.f,t1=0.f,t2=0.f,t3=0.f;
  #pragma unroll
  for (int j=0;j<32;j++){
    float qb = __shfl(q, j, 32);
    float wv = WkL[c*33 + j];
    if (j<8)       t0 = fmaf(wv, qb, t0);
    else if (j<16) t1 = fmaf(wv, qb, t1);
    else if (j<24) t2 = fmaf(wv, qb, t2);
    else           t3 = fmaf(wv, qb, t3);
  }
  *(float4*)(Tq + (size_t)n*128 + c*4) = make_float4(t0,t1,t2,t3);
}

// ---------- zero agg buffer + den ----------
__global__ __launch_bounds__(256) void k_zeroagg(float* __restrict__ fo, float* __restrict__ den){
  int i = blockIdx.x*256 + threadIdx.x;   // 33750*256 = NN*288 exactly
  fo[i] = 0.f;
  if (i < NN*4) den[i] = 0.f;
}

// DPP reduction: x += partner (involutive perms), VALU pipe. HW-proven R7/R8/R9.
template<int CTRL>
__device__ __forceinline__ float dpp_add(float x){
  return x + __int_as_float(__builtin_amdgcn_mov_dpp(__float_as_int(x), CTRL, 0xF, 0xF, true));
}
__device__ __forceinline__ float red32(float p){
  p = dpp_add<0xB1>(p);    // quad xor1
  p = dpp_add<0x4E>(p);    // quad xor2
  p = dpp_add<0x141>(p);   // row_half_mirror (pairs quads within 8)
  p = dpp_add<0x140>(p);   // row_mirror (pairs 8-groups within 16)
  p += __shfl_xor(p, 16, 32);
  return p;
}

// ---------- fused edge pass: R6 structure (proven 624us/212VGPR) + vector gathers ----------
// 4 edges/wave-iteration, W2 b128 stream amortized over 4 edges; rv/h broadcasts
// via LDS; geometry staged as float4; branchless duplicate-lane prefetch.
// vs R6: f1..f8 = 2 float4 loads (was 8 scalar), T = 1 float4 (was 4 scalar),
// red32 DPP butterfly (8 bperms, was 24). NO new pipeline state; plain
// launch_bounds(256) (R7: never force occupancy; R8/R9: no deeper state).
template<int FIRST>
__global__ __launch_bounds__(256) void k_fused(
    const float* __restrict__ pos, const float* __restrict__ ef,
    const int* __restrict__ src, const int* __restrict__ dst,
    const int* __restrict__ perm,
    const float* __restrict__ f_in, const float* __restrict__ Tq,
    const float* __restrict__ Wr1g, const float* __restrict__ br1g,
    const float* __restrict__ Wr2g,
    float* __restrict__ aggG, float* __restrict__ den)
{
  __shared__ __align__(16) float W2A[4096];
  __shared__ __align__(16) float W2B[FIRST ? 4 : 4096];
  __shared__ __align__(16) float rvL[4][4][32];
  __shared__ __align__(16) float hL [4][4][32];
  __shared__ float4 geoL[4][16];
  int tid = threadIdx.x;
  if (FIRST){
    for (int t=tid;t<4096;t+=256){
      int ci=t>>7, r=t&127, c0=r>>2, j=r&3;
      int k = (j==0)?0:((j==1)?3:((j==2)?5:-1));
      W2A[t] = (k>=0)? Wr2g[ci*224 + k*32 + c0] : 0.f;
    }
  } else {
    for (int t=tid;t<4096;t+=256){
      int ci=t>>7, r=t&127, c0=r>>2, j=r&3;
      W2A[t] = Wr2g[ci*224 + j*32 + c0];
      int k = j+4;
      W2B[t] = (k<7)? Wr2g[ci*224 + k*32 + c0] : 0.f;
    }
  }
  __syncthreads();

  int lane = tid & 63;
  int wv   = tid >> 6;
  int c    = lane & 31;
  int half = lane >> 5;
  int hh   = c >> 3;
  int base = blockIdx.x*64 + wv*16;      // 7500*64 = 480000 exact
  int ll   = lane & 15;

  // W1 column in registers (zero DS on weight side of h-loop)
  float w1r[33];
  #pragma unroll
  for (int j=0;j<33;j++) w1r[j] = Wr1g[j*32 + c];
  float b1 = br1g[c];

  // ---- lane-owned edge (ll); lanes 16..31 duplicate 0..15 ----
  int eL = perm[base + ll];
  int sL = src[eL];
  int dL = dst[eL];
  {
    float pdx = pos[dL*3+0]-pos[sL*3+0];
    float pdy = pos[dL*3+1]-pos[sL*3+1];
    float pdz = pos[dL*3+2]-pos[sL*3+2];
    float rr = sqrtf(pdx*pdx+pdy*pdy+pdz*pdz+1e-8f);
    float iv = 1.f/rr;
    if (lane < 16) geoL[wv][ll] = make_float4(rr, pdx*iv, pdy*iv, pdz*iv);
  }

  // ---- prologue gathers for iteration 0 (edges 2*half, 2*half+1) ----
  int eA = __shfl(eL, 2*half,   32);
  int eB = __shfl(eL, 2*half+1, 32);
  int sA = __shfl(sL, 2*half,   32);
  int sB = __shfl(sL, 2*half+1, 32);
  int dA = __shfl(dL, 2*half,   32);
  int dB = __shfl(dL, 2*half+1, 32);
  float rvPa = ef[(size_t)eA*32 + c];
  float rvPb = ef[(size_t)eB*32 + c];
  const float* fsA = f_in + (size_t)sA*288;
  const float* fsB = f_in + (size_t)sB*288;
  float fa0 = fsA[c], fb0 = fsB[c];
  float fa1=0.f,fa2=0.f,fa3=0.f,fa4=0.f,fa5=0.f,fa6=0.f,fa7=0.f,fa8=0.f;
  float fb1=0.f,fb2=0.f,fb3=0.f,fb4=0.f,fb5=0.f,fb6=0.f,fb7=0.f,fb8=0.f;
  if (!FIRST){
    float4 ua = *(const float4*)(fsA + 32 + c*8);
    float4 va = *(const float4*)(fsA + 32 + c*8 + 4);
    float4 ub = *(const float4*)(fsB + 32 + c*8);
    float4 vb = *(const float4*)(fsB + 32 + c*8 + 4);
    fa1=ua.x; fa2=ua.y; fa3=ua.z; fa4=ua.w; fa5=va.x; fa6=va.y; fa7=va.z; fa8=va.w;
    fb1=ub.x; fb2=ub.y; fb3=ub.z; fb4=ub.w; fb5=vb.x; fb6=vb.y; fb7=vb.z; fb8=vb.w;
  }
  float4 TAv = *(const float4*)(Tq + (size_t)dA*128 + c*4);
  float4 TBv = *(const float4*)(Tq + (size_t)dB*128 + c*4);
  float Ta0=TAv.x, Ta1=TAv.y, Ta2=TAv.z, Ta3=TAv.w;
  float Tb0=TBv.x, Tb1=TBv.y, Tb2=TBv.z, Tb3=TBv.w;

  float A[9];
  #pragma unroll
  for (int j=0;j<9;j++) A[j]=0.f;
  float denA = 0.f;
  int curd = -1;

  #pragma unroll 1
  for (int it=0; it<4; ++it){
    // ---- capture current ----
    int dCa = dA, dCb = dB;
    float ca0=fa0,ca1=fa1,ca2=fa2,ca3=fa3,ca4=fa4,ca5=fa5,ca6=fa6,ca7=fa7,ca8=fa8;
    float cb0=fb0,cb1=fb1,cb2=fb2,cb3=fb3,cb4=fb4,cb5=fb5,cb6=fb6,cb7=fb7,cb8=fb8;
    float Sa0=Ta0,Sa1=Ta1,Sa2=Ta2,Sa3=Ta3;
    float Sb0=Tb0,Sb1=Tb1,Sb2=Tb2,Sb3=Tb3;
    // commit staged ef rows (loads issued last iteration -> latency hidden)
    rvL[wv][half*2+0][c] = rvPa;
    rvL[wv][half*2+1][c] = rvPb;

    // ---- branchless prefetch of iteration it+1 (it=3 -> lanes 16..19 dummy) ----
    {
      int ia = (it+1)*4 + 2*half, ib = ia+1;
      eA = __shfl(eL, ia, 32); eB = __shfl(eL, ib, 32);
      sA = __shfl(sL, ia, 32); sB = __shfl(sL, ib, 32);
      dA = __shfl(dL, ia, 32); dB = __shfl(dL, ib, 32);
      rvPa = ef[(size_t)eA*32 + c];
      rvPb = ef[(size_t)eB*32 + c];
      const float* fsA2 = f_in + (size_t)sA*288;
      const float* fsB2 = f_in + (size_t)sB*288;
      fa0 = fsA2[c]; fb0 = fsB2[c];
      if (!FIRST){
        float4 ua = *(const float4*)(fsA2 + 32 + c*8);
        float4 va = *(const float4*)(fsA2 + 32 + c*8 + 4);
        float4 ub = *(const float4*)(fsB2 + 32 + c*8);
        float4 vb = *(const float4*)(fsB2 + 32 + c*8 + 4);
        fa1=ua.x; fa2=ua.y; fa3=ua.z; fa4=ua.w; fa5=va.x; fa6=va.y; fa7=va.z; fa8=va.w;
        fb1=ub.x; fb2=ub.y; fb3=ub.z; fb4=ub.w; fb5=vb.x; fb6=vb.y; fb7=vb.z; fb8=vb.w;
      }
      float4 TA2 = *(const float4*)(Tq + (size_t)dA*128 + c*4);
      float4 TB2 = *(const float4*)(Tq + (size_t)dB*128 + c*4);
      Ta0=TA2.x; Ta1=TA2.y; Ta2=TA2.z; Ta3=TA2.w;
      Tb0=TB2.x; Tb1=TB2.y; Tb2=TB2.z; Tb3=TB2.w;
    }

    // ---- geometry for current edges (uniform-per-half LDS read) ----
    int ea_idx = it*4 + 2*half;
    float4 ga = geoL[wv][ea_idx];
    float4 gb = geoL[wv][ea_idx+1];

    // ---- h for both edges (rv via uniform float4 LDS reads) ----
    float ha0 = fmaf(ga.x, w1r[0], b1), ha1=0.f, ha2=0.f, ha3=0.f;
    float hb0 = fmaf(gb.x, w1r[0], b1), hb1=0.f, hb2=0.f, hb3=0.f;
    #pragma unroll
    for (int jb=0;jb<8;jb++){
      float4 ra = *(const float4*)&rvL[wv][half*2+0][jb*4];
      float4 rb = *(const float4*)&rvL[wv][half*2+1][jb*4];
      ha0 = fmaf(ra.x, w1r[1+jb*4+0], ha0);
      ha1 = fmaf(ra.y, w1r[1+jb*4+1], ha1);
      ha2 = fmaf(ra.z, w1r[1+jb*4+2], ha2);
      ha3 = fmaf(ra.w, w1r[1+jb*4+3], ha3);
      hb0 = fmaf(rb.x, w1r[1+jb*4+0], hb0);
      hb1 = fmaf(rb.y, w1r[1+jb*4+1], hb1);
      hb2 = fmaf(rb.z, w1r[1+jb*4+2], hb2);
      hb3 = fmaf(rb.w, w1r[1+jb*4+3], hb3);
    }
    float hA = fmaxf((ha0+ha1)+(ha2+ha3), 0.f);
    float hB = fmaxf((hb0+hb1)+(hb2+hb3), 0.f);
    hL[wv][half*2+0][c] = hA;
    hL[wv][half*2+1][c] = hB;

    // ---- w = h @ W2 for both edges; W2 reads amortized over 4 edges ----
    float wa0=0.f,wa1=0.f,wa2=0.f,wa3=0.f,wa4=0.f,wa5=0.f,wa6=0.f;
    float wb0=0.f,wb1=0.f,wb2=0.f,wb3=0.f,wb4=0.f,wb5=0.f,wb6=0.f;
    #pragma unroll
    for (int c4=0;c4<8;c4++){
      float4 ha4 = *(const float4*)&hL[wv][half*2+0][c4*4];
      float4 hb4 = *(const float4*)&hL[wv][half*2+1][c4*4];
      #pragma unroll
      for (int j=0;j<4;j++){
        int ci = c4*4+j;
        float haj = (j==0)?ha4.x:((j==1)?ha4.y:((j==2)?ha4.z:ha4.w));
        float hbj = (j==0)?hb4.x:((j==1)?hb4.y:((j==2)?hb4.z:hb4.w));
        float4 qa = *(const float4*)&W2A[ci*128 + c*4];
        if (FIRST){
          wa0 = fmaf(haj, qa.x, wa0); wa3 = fmaf(haj, qa.y, wa3); wa5 = fmaf(haj, qa.z, wa5);
          wb0 = fmaf(hbj, qa.x, wb0); wb3 = fmaf(hbj, qa.y, wb3); wb5 = fmaf(hbj, qa.z, wb5);
        } else {
          float4 qb = *(const float4*)&W2B[ci*128 + c*4];
          wa0 = fmaf(haj, qa.x, wa0); wa1 = fmaf(haj, qa.y, wa1);
          wa2 = fmaf(haj, qa.z, wa2); wa3 = fmaf(haj, qa.w, wa3);
          wa4 = fmaf(haj, qb.x, wa4); wa5 = fmaf(haj, qb.y, wa5);
          wa6 = fmaf(haj, qb.z, wa6);
          wb0 = fmaf(hbj, qa.x, wb0); wb1 = fmaf(hbj, qa.y, wb1);
          wb2 = fmaf(hbj, qa.z, wb2); wb3 = fmaf(hbj, qa.w, wb3);
          wb4 = fmaf(hbj, qb.x, wb4); wb5 = fmaf(hbj, qb.y, wb5);
          wb6 = fmaf(hbj, qb.z, wb6);
        }
      }
    }

    // ---- messages ----
    float y2aA=ga.y*ga.z, y2bA=ga.z*ga.w, y2cA=3.f*ga.w*ga.w-1.f, y2dA=ga.y*ga.w, y2eA=ga.y*ga.y-ga.z*ga.z;
    float y2aB=gb.y*gb.z, y2bB=gb.z*gb.w, y2cB=3.f*gb.w*gb.w-1.f, y2dB=gb.y*gb.w, y2eB=gb.y*gb.y-gb.z*gb.z;
    float m0A = wa0*ca0;
    float m0B = wb0*cb0;
    if (!FIRST){
      m0A += wa1*(ca1*ga.y+ca2*ga.z+ca3*ga.w)
           + wa2*(ca4*y2aA+ca5*y2bA+ca6*y2cA+ca7*y2dA+ca8*y2eA);
      m0B += wb1*(cb1*gb.y+cb2*gb.z+cb3*gb.w)
           + wb2*(cb4*y2aB+cb5*y2bB+cb6*y2cB+cb7*y2dB+cb8*y2eB);
    }

    // ---- logits: per-lane products + red32 DPP butterfly ----
    float pa0 = red32(m0A*Sa0), pa1 = red32(m0A*Sa1);
    float pa2 = red32(m0A*Sa2), pa3 = red32(m0A*Sa3);
    float pb0 = red32(m0B*Sb0), pb1 = red32(m0B*Sb1);
    float pb2 = red32(m0B*Sb2), pb3 = red32(m0B*Sb3);
    float ShA = (hh==0)?pa0:((hh==1)?pa1:((hh==2)?pa2:pa3));
    float ShB = (hh==0)?pb0:((hh==1)?pb1:((hh==2)?pb2:pb3));
    float elA = __expf(ShA * 0.35355339059327373f);   // 1/sqrt(8); logits O(1)
    float elB = __expf(ShB * 0.35355339059327373f);

    // ---- edge A: flush + accumulate ----
    if (dCa != curd){
      if (curd >= 0){
        #pragma unroll
        for (int j=0;j<9;j++) atomicAdd(&aggG[(size_t)curd*288 + j*32 + c], A[j]);
        if ((c&7)==0) atomicAdd(&den[(size_t)curd*4 + hh], denA);
      }
      #pragma unroll
      for (int j=0;j<9;j++) A[j]=0.f;
      denA = 0.f;
      curd = dCa;
    }
    denA += elA;
    A[0] = fmaf(elA, m0A, A[0]);
    A[1] = fmaf(elA, wa3*ca0*ga.y + wa4*ca1, A[1]);
    A[2] = fmaf(elA, wa3*ca0*ga.z + wa4*ca2, A[2]);
    A[3] = fmaf(elA, wa3*ca0*ga.w + wa4*ca3, A[3]);
    A[4] = fmaf(elA, wa5*ca0*y2aA + wa6*ca4, A[4]);
    A[5] = fmaf(elA, wa5*ca0*y2bA + wa6*ca5, A[5]);
    A[6] = fmaf(elA, wa5*ca0*y2cA + wa6*ca6, A[6]);
    A[7] = fmaf(elA, wa5*ca0*y2dA + wa6*ca7, A[7]);
    A[8] = fmaf(elA, wa5*ca0*y2eA + wa6*ca8, A[8]);

    // ---- edge B: flush + accumulate ----
    if (dCb != curd){
      if (curd >= 0){
        #pragma unroll
        for (int j=0;j<9;j++) atomicAdd(&aggG[(size_t)curd*288 + j*32 + c], A[j]);
        if ((c&7)==0) atomicAdd(&den[(size_t)curd*4 + hh], denA);
      }
      #pragma unroll
      for (int j=0;j<9;j++) A[j]=0.f;
      denA = 0.f;
      curd = dCb;
    }
    denA += elB;
    A[0] = fmaf(elB, m0B, A[0]);
    A[1] = fmaf(elB, wb3*cb0*gb.y + wb4*cb1, A[1]);
    A[2] = fmaf(elB, wb3*cb0*gb.z + wb4*cb2, A[2]);
    A[3] = fmaf(elB, wb3*cb0*gb.w + wb4*cb3, A[3]);
    A[4] = fmaf(elB, wb5*cb0*y2aB + wb6*cb4, A[4]);
    A[5] = fmaf(elB, wb5*cb0*y2bB + wb6*cb5, A[5]);
    A[6] = fmaf(elB, wb5*cb0*y2cB + wb6*cb6, A[6]);
    A[7] = fmaf(elB, wb5*cb0*y2dB + wb6*cb7, A[7]);
    A[8] = fmaf(elB, wb5*cb0*y2eB + wb6*cb8, A[8]);
  }
  if (curd >= 0){
    #pragma unroll
    for (int j=0;j<9;j++) atomicAdd(&aggG[(size_t)curd*288 + j*32 + c], A[j]);
    if ((c&7)==0) atomicAdd(&den[(size_t)curd*4 + hh], denA);
  }
}

// ---------- node update: agg-layout in -> feature-layout out (in place, synced) ----------
__global__ __launch_bounds__(256) void k_update(
    const float* __restrict__ aggG, const float* __restrict__ f_in,
    const float* __restrict__ den,
    const float* __restrict__ Ws0, const float* __restrict__ Ws1,
    const float* __restrict__ Ws2, const float* __restrict__ Wsk,
    float* __restrict__ f_out)
{
  __shared__ float wL[4096];
  __shared__ float agL[8][297];
  __shared__ float f0L[8][33];
  __shared__ float dL[8][4];
  int tid = threadIdx.x;
  int nb = blockIdx.x*8;
  for (int i=tid;i<1024;i+=256){
    wL[i]=Ws0[i]; wL[1024+i]=Ws1[i]; wL[2048+i]=Ws2[i]; wL[3072+i]=Wsk[i];
  }
  if (tid < 32){
    int nl = tid>>2, hd = tid&3;
    dL[nl][hd] = 1.f/(den[(size_t)(nb+nl)*4 + hd] + 1e-30f);
  }
  { int nl=tid>>5, cc=tid&31; f0L[nl][cc] = f_in[(size_t)(nb+nl)*288 + cc]; }
  __syncthreads();
  for (int i=tid;i<2304;i+=256){
    int nl=i/288, F=i-nl*288, r=F>>5, cc=F&31;
    agL[nl][r*33+cc] = aggG[(size_t)(nb+nl)*288 + F] * dL[nl][cc>>3];
  }
  __syncthreads();
  int nl = tid>>5, o = tid&31;
  size_t obase = (size_t)(nb+nl)*288;
  float accv[9];
  #pragma unroll
  for (int r=0;r<9;r++){
    const float* W = (r==0)? wL : ((r<4)? wL+1024 : wL+2048);
    float acc=0.f;
    #pragma unroll
    for (int cc=0;cc<32;cc++) acc = fmaf(agL[nl][r*33+cc], W[cc*32+o], acc);
    if (r==0){
      #pragma unroll
      for (int cc=0;cc<32;cc++) acc = fmaf(f0L[nl][cc], wL[3072 + cc*32+o], acc);
    }
    accv[r] = acc;
  }
  f_out[obase + o] = accv[0];
  *(float4*)(f_out + obase + 32 + o*8)     = make_float4(accv[1],accv[2],accv[3],accv[4]);
  *(float4*)(f_out + obase + 32 + o*8 + 4) = make_float4(accv[5],accv[6],accv[7],accv[8]);
}

// ---------- output head (f32 out; reads only f0 region, layout-unchanged) ----------
__global__ __launch_bounds__(256) void k_out(
    const float* __restrict__ f_in, const float* __restrict__ Wout,
    const float* __restrict__ Wc, float* __restrict__ out)
{
  __shared__ float sh[8][33];
  int tid = threadIdx.x;
  int nl = tid>>5, c = tid&31;
  int n = blockIdx.x*8 + nl;
  const float* f0 = f_in + (size_t)n*288;
  float acc=0.f;
  #pragma unroll
  for (int ci=0;ci<32;ci++) acc = fmaf(f0[ci], Wout[ci*32+c], acc);
  out[(size_t)n*32 + c] = acc;
  sh[nl][c] = acc;
  __syncthreads();
  if (tid < 120){
    int nl2 = tid/15, j = tid%15;
    int n2 = blockIdx.x*8 + nl2;
    float a = 0.f;
    #pragma unroll
    for (int ci=0;ci<32;ci++) a = fmaf(sh[nl2][ci], Wc[ci*15+j], a);
    out[(size_t)NN*32 + (size_t)n2*15 + j] = a;
  }
}

extern "C" void kernel_launch(void* const* d_in, const int* in_sizes, int n_in,
                              void* d_out, int out_size, void* d_ws, size_t ws_size,
                              hipStream_t stream)
{
  (void)in_sizes; (void)n_in;
  const float* pos       = (const float*)d_in[0];
  const float* node_l0   = (const float*)d_in[1];
  const float* edge_feat = (const float*)d_in[2];
  const int* esrc = (const int*)d_in[3];
  const int* edst = (const int*)d_in[4];
  const float* Wr1  = (const float*)d_in[5];
  const float* br1  = (const float*)d_in[6];
  const float* Wr2  = (const float*)d_in[7];
  const float* Wq   = (const float*)d_in[8];
  const float* Wk   = (const float*)d_in[9];
  const float* Ws0  = (const float*)d_in[10];
  const float* Ws1  = (const float*)d_in[11];
  const float* Ws2  = (const float*)d_in[12];
  const float* Wsk  = (const float*)d_in[13];
  const float* Wout = (const float*)d_in[14];
  const float* Wc   = (const float*)d_in[15];

  char* ws = (char*)d_ws;
  size_t off = 0;
  auto take = [&](size_t bytes)->char*{
    char* p = ws + off;
    off += (bytes + 255) & ~(size_t)255;
    return p;
  };
  float* fA      = (float*)take((size_t)NN*288*4);
  float* fB      = (float*)take((size_t)NN*288*4);
  float* Tq      = (float*)take((size_t)NN*128*4);
  int*   hist    = (int*)  take((size_t)NN*4);
  int*   offs    = (int*)  take((size_t)(NN+1)*4);
  int*   cursor  = (int*)  take((size_t)NN*4);
  int*   perm    = (int*)  take((size_t)EE*4);
  float* den     = (float*)take((size_t)NN*4*4);
  size_t need = off;                                  // ~88 MB (unchanged)

  if (ws_size < need){
    k_zero<<<(out_size+255)/256,256,0,stream>>>((float*)d_out, out_size);
    return;
  }

  k_init<<<33750,256,0,stream>>>(node_l0, fA, hist);
  k_hist<<<1875,256,0,stream>>>(edst, hist);
  k_scan<<<1,1024,0,stream>>>(hist, offs, cursor, NN);
  k_scatter<<<1875,256,0,stream>>>(edst, cursor, perm);

  float* fi = fA; float* fo = fB;
  for (int l=0; l<2; ++l){
    k_zeroagg<<<33750,256,0,stream>>>(fo, den);
    k_qt<<<3750,256,0,stream>>>(fi, Wq + l*1024, Wk + l*1024, Tq);
    if (l==0){
      k_fused<1><<<7500,256,0,stream>>>(pos, edge_feat, esrc, edst, perm,
          fi, Tq, Wr1 + l*1056, br1 + l*32, Wr2 + l*7168,
          fo, den);
    } else {
      k_fused<0><<<7500,256,0,stream>>>(pos, edge_feat, esrc, edst, perm,
          fi, Tq, Wr1 + l*1056, br1 + l*32, Wr2 + l*7168,
          fo, den);
    }
    k_update<<<3750,256,0,stream>>>(fo, fi, den,
        Ws0 + l*1024, Ws1 + l*1024, Ws2 + l*1024, Wsk + l*1024, fo);
    float* tmp = fi; fi = fo; fo = tmp;
  }
  k_out<<<3750,256,0,stream>>>(fi, Wout, Wc, (float*)d_out);
}

// Round 12
// 1029.123 us; speedup vs baseline: 4.9760x; 1.2367x over previous
//
#include <hip/hip_runtime.h>
#include <hip/hip_fp16.h>

#define NN 30000
#define EE 480000

// Feature row layout (288 floats/node):
//   [0..31]  f0 channel-dense; [32..287] f1..f8 channel-major (32 + c*8 + (j-1))
// Tq layout: [n][32][4] (float4 per (node,channel)).

// ---------- zero-fill fallback (ws too small diagnostic) ----------
__global__ __launch_bounds__(256) void k_zero(float* __restrict__ out, int n){
  int i = blockIdx.x*256 + threadIdx.x;
  if (i < n) out[i] = 0.f;
}

// ---------- node feature init ----------
__global__ __launch_bounds__(256) void k_init(
    const float* __restrict__ nl0, float* __restrict__ fA, int* __restrict__ hist)
{
  int i = blockIdx.x*256 + threadIdx.x;   // exactly N*288
  int n = i/288; int r2 = i - n*288;
  fA[i] = (r2 < 32) ? nl0[(size_t)n*32 + r2] : 0.f;
  if (i < NN) hist[i] = 0;
}

__global__ __launch_bounds__(256) void k_hist(const int* __restrict__ dst, int* __restrict__ hist){
  int e = blockIdx.x*256 + threadIdx.x;
  if (e < EE) atomicAdd(&hist[dst[e]], 1);
}

__global__ void k_scan(const int* __restrict__ hist, int* __restrict__ offs,
                       int* __restrict__ cursor, int n)
{
  __shared__ int sm[1024];
  __shared__ int carry;
  int tid = threadIdx.x;
  if (tid==0) carry = 0;
  __syncthreads();
  for (int base=0; base<n; base+=1024){
    int i = base + tid;
    int v = (i<n)? hist[i] : 0;
    sm[tid] = v; __syncthreads();
    for (int o=1;o<1024;o<<=1){
      int tv = (tid>=o)? sm[tid-o] : 0;
      __syncthreads();
      sm[tid] += tv;
      __syncthreads();
    }
    int cy = carry;
    int excl = sm[tid] - v;
    if (i<n){ offs[i] = cy+excl; cursor[i] = cy+excl; }
    __syncthreads();
    if (tid==1023) carry = cy + sm[1023];
    __syncthreads();
  }
  if (tid==0) offs[n] = carry;
}

__global__ __launch_bounds__(256) void k_scatter(const int* __restrict__ dst,
    int* __restrict__ cursor, int* __restrict__ perm)
{
  int e = blockIdx.x*256 + threadIdx.x;
  if (e >= EE) return;
  int d = dst[e];
  int p = atomicAdd(&cursor[d], 1);
  perm[p] = e;
}

// ---------- per-node q projection folded into T; Tq stored [n][32][4] ----------
__global__ __launch_bounds__(256) void k_qt(
    const float* __restrict__ f_in, const float* __restrict__ Wqf,
    const float* __restrict__ Wkf, float* __restrict__ Tq)
{
  __shared__ float WqL[1024];
  __shared__ float WkL[1056];           // [c][33] padded
  int tid = threadIdx.x;
  for (int i=tid;i<1024;i+=256) WqL[i]=Wqf[i];
  for (int i=tid;i<1056;i+=256){ int r=i/33, o=i-r*33; if (o<32) WkL[i]=Wkf[r*32+o]; }
  __syncthreads();
  int n = blockIdx.x*8 + (tid>>5), c = tid&31;
  const float* f0 = f_in + (size_t)n*288;
  float q=0.f;
  #pragma unroll
  for (int ci=0;ci<32;ci++) q = fmaf(f0[ci], WqL[ci*32+c], q);
  float t0=0.f,t1=0.f,t2=0.f,t3=0.f;
  #pragma unroll
  for (int j=0;j<32;j++){
    float qb = __shfl(q, j, 32);
    float wv = WkL[c*33 + j];
    if (j<8)       t0 = fmaf(wv, qb, t0);
    else if (j<16) t1 = fmaf(wv, qb, t1);
    else if (j<24) t2 = fmaf(wv, qb, t2);
    else           t3 = fmaf(wv, qb, t3);
  }
  *(float4*)(Tq + (size_t)n*128 + c*4) = make_float4(t0,t1,t2,t3);
}

// ---------- zero agg buffer + den ----------
__global__ __launch_bounds__(256) void k_zeroagg(float* __restrict__ fo, float* __restrict__ den){
  int i = blockIdx.x*256 + threadIdx.x;
  fo[i] = 0.f;
  if (i < NN*4) den[i] = 0.f;
}

// DPP reduction (VALU pipe), HW-proven R7-R10
template<int CTRL>
__device__ __forceinline__ float dpp_add(float x){
  return x + __int_as_float(__builtin_amdgcn_mov_dpp(__float_as_int(x), CTRL, 0xF, 0xF, true));
}
__device__ __forceinline__ float red32(float p){
  p = dpp_add<0xB1>(p);
  p = dpp_add<0x4E>(p);
  p = dpp_add<0x141>(p);
  p = dpp_add<0x140>(p);
  p += __shfl_xor(p, 16, 32);
  return p;
}

__device__ __forceinline__ unsigned pkh(float a, float b){
  __half2 h2; h2.x = __float2half_rn(a); h2.y = __float2half_rn(b);
  return *reinterpret_cast<unsigned*>(&h2);
}
__device__ __forceinline__ float2 uph(unsigned u){
  __half2 h2 = *reinterpret_cast<__half2*>(&u);
  return __half22float2(h2);
}

// ---------- fused edge pass: per-wave 3-phase split ----------
// Each wave owns 16 edges. Phase H: h for all 16 (rv via LDS, W1 in regs) ->
// hT[ci][e] transposed (pad 20, b128-aligned). Phase W: dense w=h@W2 GEMM,
// each lane does its half's 8 edges -> W2 b128 amortized 8x, h reads are
// UNIFORM broadcasts; results stored to wH: FIRST = raw fp32 bits in uint4
// (exact, fixes R11's w3/w5 unpack bug), !FIRST = fp16 x7 (verified layout).
// Phase A: slim gather loop (w read = 1 uint4/edge). No inter-phase barriers
// (wave-private LDS, program order). Plain launch_bounds(256).
template<int FIRST>
__global__ __launch_bounds__(256) void k_fused(
    const float* __restrict__ pos, const float* __restrict__ ef,
    const int* __restrict__ src, const int* __restrict__ dst,
    const int* __restrict__ perm,
    const float* __restrict__ f_in, const float* __restrict__ Tq,
    const float* __restrict__ Wr1g, const float* __restrict__ br1g,
    const float* __restrict__ Wr2g,
    float* __restrict__ aggG, float* __restrict__ den)
{
  __shared__ __align__(16) float W2A[4096];
  __shared__ __align__(16) float W2B[FIRST ? 4 : 4096];
  __shared__ __align__(16) float hT[4][32][20];    // [wave][ci][edge(16)+pad4]
  __shared__ __align__(16) uint4 wH[4][16][32];    // per (edge,c) packed w
  __shared__ __align__(16) float rvL[4][2][32];
  __shared__ float4 geoL[4][16];
  int tid = threadIdx.x;
  if (FIRST){
    for (int t=tid;t<4096;t+=256){
      int ci=t>>7, r=t&127, c0=r>>2, j=r&3;
      int k = (j==0)?0:((j==1)?3:((j==2)?5:-1));
      W2A[t] = (k>=0)? Wr2g[ci*224 + k*32 + c0] : 0.f;
    }
  } else {
    for (int t=tid;t<4096;t+=256){
      int ci=t>>7, r=t&127, c0=r>>2, j=r&3;
      W2A[t] = Wr2g[ci*224 + j*32 + c0];
      int k = j+4;
      W2B[t] = (k<7)? Wr2g[ci*224 + k*32 + c0] : 0.f;
    }
  }
  __syncthreads();

  int lane = tid & 63;
  int wv   = tid >> 6;
  int c    = lane & 31;
  int half = lane >> 5;
  int hh   = c >> 3;
  int base = blockIdx.x*64 + wv*16;      // 7500*64 = 480000 exact
  int ll   = lane & 15;

  // W1 column in registers (phase H only; dead afterwards)
  float w1r[33];
  #pragma unroll
  for (int j=0;j<33;j++) w1r[j] = Wr1g[j*32 + c];
  float b1 = br1g[c];

  // ---- lane-owned edge (ll); lanes 16..31 duplicate 0..15 ----
  int eL = perm[base + ll];
  int sL = src[eL];
  int dL = dst[eL];
  {
    float pdx = pos[dL*3+0]-pos[sL*3+0];
    float pdy = pos[dL*3+1]-pos[sL*3+1];
    float pdz = pos[dL*3+2]-pos[sL*3+2];
    float rr = sqrtf(pdx*pdx+pdy*pdy+pdz*pdz+1e-8f);
    float iv = 1.f/rr;
    if (lane < 16) geoL[wv][ll] = make_float4(rr, pdx*iv, pdy*iv, pdz*iv);
  }

  // ================= Phase H: h for this half's 8 edges =================
  {
    int e0 = __shfl(eL, half*8, 32);
    float rvP = ef[(size_t)e0*32 + c];
    #pragma unroll 1
    for (int si=0; si<8; ++si){
      rvL[wv][half][c] = rvP;
      int idn = half*8 + si + 1;           // half1 si=7 -> idx16 = dup lane, valid
      int eN = __shfl(eL, idn, 32);
      rvP = ef[(size_t)eN*32 + c];
      float4 g = geoL[wv][half*8 + si];
      float h0 = fmaf(g.x, w1r[0], b1), h1=0.f, h2=0.f, h3=0.f;
      #pragma unroll
      for (int jb=0;jb<8;jb++){
        float4 r4 = *(const float4*)&rvL[wv][half][jb*4];
        h0 = fmaf(r4.x, w1r[1+jb*4+0], h0);
        h1 = fmaf(r4.y, w1r[1+jb*4+1], h1);
        h2 = fmaf(r4.z, w1r[1+jb*4+2], h2);
        h3 = fmaf(r4.w, w1r[1+jb*4+3], h3);
      }
      hT[wv][c][half*8 + si] = fmaxf((h0+h1)+(h2+h3), 0.f);
    }
  }

  // ================= Phase W: dense w = h @ W2 for 8 edges/lane =================
  {
    int eb = half*8;
    if (FIRST){
      float a0[8], a3[8], a5[8];
      #pragma unroll
      for (int j=0;j<8;j++){ a0[j]=0.f; a3[j]=0.f; a5[j]=0.f; }
      #pragma unroll
      for (int ci=0;ci<32;ci++){
        float4 qa = *(const float4*)&W2A[ci*128 + c*4];
        float4 h03 = *(const float4*)&hT[wv][ci][eb];      // uniform per half
        float4 h47 = *(const float4*)&hT[wv][ci][eb+4];
        float hv[8] = {h03.x,h03.y,h03.z,h03.w,h47.x,h47.y,h47.z,h47.w};
        #pragma unroll
        for (int j=0;j<8;j++){
          a0[j] = fmaf(hv[j], qa.x, a0[j]);
          a3[j] = fmaf(hv[j], qa.y, a3[j]);
          a5[j] = fmaf(hv[j], qa.z, a5[j]);
        }
      }
      // exact fp32 bit store: word.x=w0, word.y=w3, word.z=w5 (R11 bug fix)
      #pragma unroll
      for (int j=0;j<8;j++){
        wH[wv][eb+j][c] = make_uint4(__float_as_uint(a0[j]),
                                     __float_as_uint(a3[j]),
                                     __float_as_uint(a5[j]), 0u);
      }
    } else {
      float a0[8],a1[8],a2[8],a3[8],a4[8],a5[8],a6[8];
      #pragma unroll
      for (int j=0;j<8;j++){ a0[j]=0.f;a1[j]=0.f;a2[j]=0.f;a3[j]=0.f;a4[j]=0.f;a5[j]=0.f;a6[j]=0.f; }
      #pragma unroll
      for (int ci=0;ci<32;ci++){
        float4 qa = *(const float4*)&W2A[ci*128 + c*4];
        float4 qb = *(const float4*)&W2B[ci*128 + c*4];
        float4 h03 = *(const float4*)&hT[wv][ci][eb];      // uniform per half
        float4 h47 = *(const float4*)&hT[wv][ci][eb+4];
        float hv[8] = {h03.x,h03.y,h03.z,h03.w,h47.x,h47.y,h47.z,h47.w};
        #pragma unroll
        for (int j=0;j<8;j++){
          a0[j] = fmaf(hv[j], qa.x, a0[j]);
          a1[j] = fmaf(hv[j], qa.y, a1[j]);
          a2[j] = fmaf(hv[j], qa.z, a2[j]);
          a3[j] = fmaf(hv[j], qa.w, a3[j]);
          a4[j] = fmaf(hv[j], qb.x, a4[j]);
          a5[j] = fmaf(hv[j], qb.y, a5[j]);
          a6[j] = fmaf(hv[j], qb.z, a6[j]);
        }
      }
      #pragma unroll
      for (int j=0;j<8;j++){
        wH[wv][eb+j][c] = make_uint4(pkh(a0[j],a1[j]), pkh(a2[j],a3[j]),
                                     pkh(a4[j],a5[j]), pkh(a6[j],0.f));
      }
    }
  }

  // ================= Phase A: slim gather/aggregate =================
  int dA, dB;
  float fa0,fa1=0.f,fa2=0.f,fa3=0.f,fa4=0.f,fa5=0.f,fa6=0.f,fa7=0.f,fa8=0.f;
  float fb0,fb1=0.f,fb2=0.f,fb3=0.f,fb4=0.f,fb5=0.f,fb6=0.f,fb7=0.f,fb8=0.f;
  float Ta0,Ta1,Ta2,Ta3, Tb0,Tb1,Tb2,Tb3;
  {
    int sA = __shfl(sL, 2*half,   32);
    int sB = __shfl(sL, 2*half+1, 32);
    dA = __shfl(dL, 2*half,   32);
    dB = __shfl(dL, 2*half+1, 32);
    const float* fsA = f_in + (size_t)sA*288;
    const float* fsB = f_in + (size_t)sB*288;
    fa0 = fsA[c]; fb0 = fsB[c];
    if (!FIRST){
      float4 ua = *(const float4*)(fsA + 32 + c*8);
      float4 va = *(const float4*)(fsA + 32 + c*8 + 4);
      float4 ub = *(const float4*)(fsB + 32 + c*8);
      float4 vb = *(const float4*)(fsB + 32 + c*8 + 4);
      fa1=ua.x; fa2=ua.y; fa3=ua.z; fa4=ua.w; fa5=va.x; fa6=va.y; fa7=va.z; fa8=va.w;
      fb1=ub.x; fb2=ub.y; fb3=ub.z; fb4=ub.w; fb5=vb.x; fb6=vb.y; fb7=vb.z; fb8=vb.w;
    }
    float4 TAv = *(const float4*)(Tq + (size_t)dA*128 + c*4);
    float4 TBv = *(const float4*)(Tq + (size_t)dB*128 + c*4);
    Ta0=TAv.x; Ta1=TAv.y; Ta2=TAv.z; Ta3=TAv.w;
    Tb0=TBv.x; Tb1=TBv.y; Tb2=TBv.z; Tb3=TBv.w;
  }

  float A[9];
  #pragma unroll
  for (int j=0;j<9;j++) A[j]=0.f;
  float denA = 0.f;
  int curd = -1;

  #pragma unroll 1
  for (int it=0; it<4; ++it){
    int dCa = dA, dCb = dB;
    float ca0=fa0,ca1=fa1,ca2=fa2,ca3=fa3,ca4=fa4,ca5=fa5,ca6=fa6,ca7=fa7,ca8=fa8;
    float cb0=fb0,cb1=fb1,cb2=fb2,cb3=fb3,cb4=fb4,cb5=fb5,cb6=fb6,cb7=fb7,cb8=fb8;
    float Sa0=Ta0,Sa1=Ta1,Sa2=Ta2,Sa3=Ta3;
    float Sb0=Tb0,Sb1=Tb1,Sb2=Tb2,Sb3=Tb3;

    // branchless prefetch of it+1 (it=3 -> dup lanes, valid dummy)
    {
      int ia = (it+1)*4 + 2*half, ib = ia+1;
      int sA = __shfl(sL, ia, 32);
      int sB = __shfl(sL, ib, 32);
      dA = __shfl(dL, ia, 32);
      dB = __shfl(dL, ib, 32);
      const float* fsA2 = f_in + (size_t)sA*288;
      const float* fsB2 = f_in + (size_t)sB*288;
      fa0 = fsA2[c]; fb0 = fsB2[c];
      if (!FIRST){
        float4 ua = *(const float4*)(fsA2 + 32 + c*8);
        float4 va = *(const float4*)(fsA2 + 32 + c*8 + 4);
        float4 ub = *(const float4*)(fsB2 + 32 + c*8);
        float4 vb = *(const float4*)(fsB2 + 32 + c*8 + 4);
        fa1=ua.x; fa2=ua.y; fa3=ua.z; fa4=ua.w; fa5=va.x; fa6=va.y; fa7=va.z; fa8=va.w;
        fb1=ub.x; fb2=ub.y; fb3=ub.z; fb4=ub.w; fb5=vb.x; fb6=vb.y; fb7=vb.z; fb8=vb.w;
      }
      float4 TA2 = *(const float4*)(Tq + (size_t)dA*128 + c*4);
      float4 TB2 = *(const float4*)(Tq + (size_t)dB*128 + c*4);
      Ta0=TA2.x; Ta1=TA2.y; Ta2=TA2.z; Ta3=TA2.w;
      Tb0=TB2.x; Tb1=TB2.y; Tb2=TB2.z; Tb3=TB2.w;
    }

    // w from LDS (1 uint4 per edge per lane)
    int ea_idx = it*4 + 2*half;
    uint4 uwa = wH[wv][ea_idx][c];
    uint4 uwb = wH[wv][ea_idx+1][c];
    float wa0,wa1=0.f,wa2=0.f,wa3,wa4=0.f,wa5,wa6=0.f;
    float wb0,wb1=0.f,wb2=0.f,wb3,wb4=0.f,wb5,wb6=0.f;
    if (FIRST){
      wa0=__uint_as_float(uwa.x); wa3=__uint_as_float(uwa.y); wa5=__uint_as_float(uwa.z);
      wb0=__uint_as_float(uwb.x); wb3=__uint_as_float(uwb.y); wb5=__uint_as_float(uwb.z);
    } else {
      float2 a01=uph(uwa.x), a23=uph(uwa.y), a45=uph(uwa.z), a6_=uph(uwa.w);
      float2 b01=uph(uwb.x), b23=uph(uwb.y), b45=uph(uwb.z), b6_=uph(uwb.w);
      wa0=a01.x; wa1=a01.y; wa2=a23.x; wa3=a23.y; wa4=a45.x; wa5=a45.y; wa6=a6_.x;
      wb0=b01.x; wb1=b01.y; wb2=b23.x; wb3=b23.y; wb4=b45.x; wb5=b45.y; wb6=b6_.x;
    }

    float4 ga = geoL[wv][ea_idx];
    float4 gb = geoL[wv][ea_idx+1];
    float y2aA=ga.y*ga.z, y2bA=ga.z*ga.w, y2cA=3.f*ga.w*ga.w-1.f, y2dA=ga.y*ga.w, y2eA=ga.y*ga.y-ga.z*ga.z;
    float y2aB=gb.y*gb.z, y2bB=gb.z*gb.w, y2cB=3.f*gb.w*gb.w-1.f, y2dB=gb.y*gb.w, y2eB=gb.y*gb.y-gb.z*gb.z;
    float m0A = wa0*ca0;
    float m0B = wb0*cb0;
    if (!FIRST){
      m0A += wa1*(ca1*ga.y+ca2*ga.z+ca3*ga.w)
           + wa2*(ca4*y2aA+ca5*y2bA+ca6*y2cA+ca7*y2dA+ca8*y2eA);
      m0B += wb1*(cb1*gb.y+cb2*gb.z+cb3*gb.w)
           + wb2*(cb4*y2aB+cb5*y2bB+cb6*y2cB+cb7*y2dB+cb8*y2eB);
    }

    float pa0 = red32(m0A*Sa0), pa1 = red32(m0A*Sa1);
    float pa2 = red32(m0A*Sa2), pa3 = red32(m0A*Sa3);
    float pb0 = red32(m0B*Sb0), pb1 = red32(m0B*Sb1);
    float pb2 = red32(m0B*Sb2), pb3 = red32(m0B*Sb3);
    float ShA = (hh==0)?pa0:((hh==1)?pa1:((hh==2)?pa2:pa3));
    float ShB = (hh==0)?pb0:((hh==1)?pb1:((hh==2)?pb2:pb3));
    float elA = __expf(ShA * 0.35355339059327373f);   // 1/sqrt(8); logits O(1)
    float elB = __expf(ShB * 0.35355339059327373f);

    if (dCa != curd){
      if (curd >= 0){
        #pragma unroll
        for (int j=0;j<9;j++) atomicAdd(&aggG[(size_t)curd*288 + j*32 + c], A[j]);
        if ((c&7)==0) atomicAdd(&den[(size_t)curd*4 + hh], denA);
      }
      #pragma unroll
      for (int j=0;j<9;j++) A[j]=0.f;
      denA = 0.f;
      curd = dCa;
    }
    denA += elA;
    A[0] = fmaf(elA, m0A, A[0]);
    A[1] = fmaf(elA, wa3*ca0*ga.y + wa4*ca1, A[1]);
    A[2] = fmaf(elA, wa3*ca0*ga.z + wa4*ca2, A[2]);
    A[3] = fmaf(elA, wa3*ca0*ga.w + wa4*ca3, A[3]);
    A[4] = fmaf(elA, wa5*ca0*y2aA + wa6*ca4, A[4]);
    A[5] = fmaf(elA, wa5*ca0*y2bA + wa6*ca5, A[5]);
    A[6] = fmaf(elA, wa5*ca0*y2cA + wa6*ca6, A[6]);
    A[7] = fmaf(elA, wa5*ca0*y2dA + wa6*ca7, A[7]);
    A[8] = fmaf(elA, wa5*ca0*y2eA + wa6*ca8, A[8]);

    if (dCb != curd){
      if (curd >= 0){
        #pragma unroll
        for (int j=0;j<9;j++) atomicAdd(&aggG[(size_t)curd*288 + j*32 + c], A[j]);
        if ((c&7)==0) atomicAdd(&den[(size_t)curd*4 + hh], denA);
      }
      #pragma unroll
      for (int j=0;j<9;j++) A[j]=0.f;
      denA = 0.f;
      curd = dCb;
    }
    denA += elB;
    A[0] = fmaf(elB, m0B, A[0]);
    A[1] = fmaf(elB, wb3*cb0*gb.y + wb4*cb1, A[1]);
    A[2] = fmaf(elB, wb3*cb0*gb.z + wb4*cb2, A[2]);
    A[3] = fmaf(elB, wb3*cb0*gb.w + wb4*cb3, A[3]);
    A[4] = fmaf(elB, wb5*cb0*y2aB + wb6*cb4, A[4]);
    A[5] = fmaf(elB, wb5*cb0*y2bB + wb6*cb5, A[5]);
    A[6] = fmaf(elB, wb5*cb0*y2cB + wb6*cb6, A[6]);
    A[7] = fmaf(elB, wb5*cb0*y2dB + wb6*cb7, A[7]);
    A[8] = fmaf(elB, wb5*cb0*y2eB + wb6*cb8, A[8]);
  }
  if (curd >= 0){
    #pragma unroll
    for (int j=0;j<9;j++) atomicAdd(&aggG[(size_t)curd*288 + j*32 + c], A[j]);
    if ((c&7)==0) atomicAdd(&den[(size_t)curd*4 + hh], denA);
  }
}

// ---------- node update: agg-layout in -> feature-layout out ----------
__global__ __launch_bounds__(256) void k_update(
    const float* __restrict__ aggG, const float* __restrict__ f_in,
    const float* __restrict__ den,
    const float* __restrict__ Ws0, const float* __restrict__ Ws1,
    const float* __restrict__ Ws2, const float* __restrict__ Wsk,
    float* __restrict__ f_out)
{
  __shared__ float wL[4096];
  __shared__ float agL[8][297];
  __shared__ float f0L[8][33];
  __shared__ float dL[8][4];
  int tid = threadIdx.x;
  int nb = blockIdx.x*8;
  for (int i=tid;i<1024;i+=256){
    wL[i]=Ws0[i]; wL[1024+i]=Ws1[i]; wL[2048+i]=Ws2[i]; wL[3072+i]=Wsk[i];
  }
  if (tid < 32){
    int nl = tid>>2, hd = tid&3;
    dL[nl][hd] = 1.f/(den[(size_t)(nb+nl)*4 + hd] + 1e-30f);
  }
  { int nl=tid>>5, cc=tid&31; f0L[nl][cc] = f_in[(size_t)(nb+nl)*288 + cc]; }
  __syncthreads();
  for (int i=tid;i<2304;i+=256){
    int nl=i/288, F=i-nl*288, r=F>>5, cc=F&31;
    agL[nl][r*33+cc] = aggG[(size_t)(nb+nl)*288 + F] * dL[nl][cc>>3];
  }
  __syncthreads();
  int nl = tid>>5, o = tid&31;
  size_t obase = (size_t)(nb+nl)*288;
  float accv[9];
  #pragma unroll
  for (int r=0;r<9;r++){
    const float* W = (r==0)? wL : ((r<4)? wL+1024 : wL+2048);
    float acc=0.f;
    #pragma unroll
    for (int cc=0;cc<32;cc++) acc = fmaf(agL[nl][r*33+cc], W[cc*32+o], acc);
    if (r==0){
      #pragma unroll
      for (int cc=0;cc<32;cc++) acc = fmaf(f0L[nl][cc], wL[3072 + cc*32+o], acc);
    }
    accv[r] = acc;
  }
  f_out[obase + o] = accv[0];
  *(float4*)(f_out + obase + 32 + o*8)     = make_float4(accv[1],accv[2],accv[3],accv[4]);
  *(float4*)(f_out + obase + 32 + o*8 + 4) = make_float4(accv[5],accv[6],accv[7],accv[8]);
}

// ---------- output head (reads only f0 region) ----------
__global__ __launch_bounds__(256) void k_out(
    const float* __restrict__ f_in, const float* __restrict__ Wout,
    const float* __restrict__ Wc, float* __restrict__ out)
{
  __shared__ float sh[8][33];
  int tid = threadIdx.x;
  int nl = tid>>5, c = tid&31;
  int n = blockIdx.x*8 + nl;
  const float* f0 = f_in + (size_t)n*288;
  float acc=0.f;
  #pragma unroll
  for (int ci=0;ci<32;ci++) acc = fmaf(f0[ci], Wout[ci*32+c], acc);
  out[(size_t)n*32 + c] = acc;
  sh[nl][c] = acc;
  __syncthreads();
  if (tid < 120){
    int nl2 = tid/15, j = tid%15;
    int n2 = blockIdx.x*8 + nl2;
    float a = 0.f;
    #pragma unroll
    for (int ci=0;ci<32;ci++) a = fmaf(sh[nl2][ci], Wc[ci*15+j], a);
    out[(size_t)NN*32 + (size_t)n2*15 + j] = a;
  }
}

extern "C" void kernel_launch(void* const* d_in, const int* in_sizes, int n_in,
                              void* d_out, int out_size, void* d_ws, size_t ws_size,
                              hipStream_t stream)
{
  (void)in_sizes; (void)n_in;
  const float* pos       = (const float*)d_in[0];
  const float* node_l0   = (const float*)d_in[1];
  const float* edge_feat = (const float*)d_in[2];
  const int* esrc = (const int*)d_in[3];
  const int* edst = (const int*)d_in[4];
  const float* Wr1  = (const float*)d_in[5];
  const float* br1  = (const float*)d_in[6];
  const float* Wr2  = (const float*)d_in[7];
  const float* Wq   = (const float*)d_in[8];
  const float* Wk   = (const float*)d_in[9];
  const float* Ws0  = (const float*)d_in[10];
  const float* Ws1  = (const float*)d_in[11];
  const float* Ws2  = (const float*)d_in[12];
  const float* Wsk  = (const float*)d_in[13];
  const float* Wout = (const float*)d_in[14];
  const float* Wc   = (const float*)d_in[15];

  char* ws = (char*)d_ws;
  size_t off = 0;
  auto take = [&](size_t bytes)->char*{
    char* p = ws + off;
    off += (bytes + 255) & ~(size_t)255;
    return p;
  };
  float* fA      = (float*)take((size_t)NN*288*4);
  float* fB      = (float*)take((size_t)NN*288*4);
  float* Tq      = (float*)take((size_t)NN*128*4);
  int*   hist    = (int*)  take((size_t)NN*4);
  int*   offs    = (int*)  take((size_t)(NN+1)*4);
  int*   cursor  = (int*)  take((size_t)NN*4);
  int*   perm    = (int*)  take((size_t)EE*4);
  float* den     = (float*)take((size_t)NN*4*4);
  size_t need = off;                                  // ~88 MB (unchanged)

  if (ws_size < need){
    k_zero<<<(out_size+255)/256,256,0,stream>>>((float*)d_out, out_size);
    return;
  }

  k_init<<<33750,256,0,stream>>>(node_l0, fA, hist);
  k_hist<<<1875,256,0,stream>>>(edst, hist);
  k_scan<<<1,1024,0,stream>>>(hist, offs, cursor, NN);
  k_scatter<<<1875,256,0,stream>>>(edst, cursor, perm);

  float* fi = fA; float* fo = fB;
  for (int l=0; l<2; ++l){
    k_zeroagg<<<33750,256,0,stream>>>(fo, den);
    k_qt<<<3750,256,0,stream>>>(fi, Wq + l*1024, Wk + l*1024, Tq);
    if (l==0){
      k_fused<1><<<7500,256,0,stream>>>(pos, edge_feat, esrc, edst, perm,
          fi, Tq, Wr1 + l*1056, br1 + l*32, Wr2 + l*7168,
          fo, den);
    } else {
      k_fused<0><<<7500,256,0,stream>>>(pos, edge_feat, esrc, edst, perm,
          fi, Tq, Wr1 + l*1056, br1 + l*32, Wr2 + l*7168,
          fo, den);
    }
    k_update<<<3750,256,0,stream>>>(fo, fi, den,
        Ws0 + l*1024, Ws1 + l*1024, Ws2 + l*1024, Wsk + l*1024, fo);
    float* tmp = fi; fi = fo; fo = tmp;
  }
  k_out<<<3750,256,0,stream>>>(fi, Wout, Wc, (float*)d_out);
}